// Round 2
// baseline (1674.575 us; speedup 1.0000x reference)
//
#include <hip/hip_runtime.h>

#define N_NODES 100000
#define N_EDGES 1600000
#define IN_CH 128
#define HID 256
#define OUT_CH 128
#define N_GRAPHS 2048

// ---------------------------------------------------------------- CSR build
__global__ void count_edges_k(const int* __restrict__ dst, int* __restrict__ deg, int E) {
    int e = blockIdx.x * blockDim.x + threadIdx.x;
    if (e < E) atomicAdd(&deg[dst[e]], 1);
}

__global__ void count_batch_k(const int* __restrict__ batch, int* __restrict__ gcnt, int n) {
    int i = blockIdx.x * blockDim.x + threadIdx.x;
    if (i < n) atomicAdd(&gcnt[batch[i]], 1);
}

// single-block exclusive scan; out has n+1 entries (out[n] = total)
__global__ void ex_scan_k(const int* __restrict__ in, int* __restrict__ out, int n) {
    __shared__ int buf[256];
    __shared__ int carry_s;
    if (threadIdx.x == 0) carry_s = 0;
    __syncthreads();
    for (int base = 0; base < n; base += 256) {
        int i = base + (int)threadIdx.x;
        int v = (i < n) ? in[i] : 0;
        buf[threadIdx.x] = v;
        __syncthreads();
        #pragma unroll
        for (int off = 1; off < 256; off <<= 1) {
            int t = (threadIdx.x >= (unsigned)off) ? buf[threadIdx.x - off] : 0;
            __syncthreads();
            buf[threadIdx.x] += t;
            __syncthreads();
        }
        int incl = buf[threadIdx.x];
        if (i < n) out[i] = carry_s + incl - v;   // exclusive
        __syncthreads();
        if (threadIdx.x == 255) carry_s += buf[255];
        __syncthreads();
    }
    if (threadIdx.x == 0) out[n] = carry_s;
}

__global__ void fill_csr_k(const int* __restrict__ src, const int* __restrict__ dst,
                           const int* __restrict__ row_ofs, int* __restrict__ cursor,
                           int* __restrict__ csr, int E) {
    int e = blockIdx.x * blockDim.x + threadIdx.x;
    if (e >= E) return;
    int d = dst[e];
    int pos = atomicAdd(&cursor[d], 1);
    csr[row_ofs[d] + pos] = src[e];
}

// ---------------------------------------------------------------- mean aggregation
// one wave per node; lane owns C/64 contiguous channels
template <int C>
__global__ void agg_mean_k(const float* __restrict__ X, const int* __restrict__ row_ofs,
                           const int* __restrict__ csr, float* __restrict__ out, int n) {
    int w = (int)((blockIdx.x * blockDim.x + threadIdx.x) >> 6);
    int lane = threadIdx.x & 63;
    if (w >= n) return;
    constexpr int V = C / 64;  // 2 or 4
    float acc[V];
    #pragma unroll
    for (int v = 0; v < V; ++v) acc[v] = 0.f;
    int s = row_ofs[w], e = row_ofs[w + 1];
    for (int j = s; j < e; ++j) {
        const float* row = X + (size_t)csr[j] * C + lane * V;
        if (V == 2) {
            float2 t = *(const float2*)row;
            acc[0] += t.x; acc[1] += t.y;
        } else {
            float4 t = *(const float4*)row;
            acc[0] += t.x; acc[1] += t.y; acc[2] += t.z; acc[3] += t.w;
        }
    }
    float inv = 1.0f / (float)max(e - s, 1);
    float* op = out + (size_t)w * C + lane * V;
    if (V == 2) {
        float2 t; t.x = acc[0] * inv; t.y = acc[1] * inv;
        *(float2*)op = t;
    } else {
        float4 t; t.x = acc[0] * inv; t.y = acc[1] * inv; t.z = acc[2] * inv; t.w = acc[3] * inv;
        *(float4*)op = t;
    }
}

// one wave per graph (batch is sorted -> contiguous row ranges)
__global__ void pool_mean_k(const float* __restrict__ H, const int* __restrict__ gofs,
                            float* __restrict__ pooled, int G) {
    int g = (int)((blockIdx.x * blockDim.x + threadIdx.x) >> 6);
    int lane = threadIdx.x & 63;
    if (g >= G) return;
    int s = gofs[g], e = gofs[g + 1];
    float a0 = 0.f, a1 = 0.f, a2 = 0.f, a3 = 0.f;
    for (int r = s; r < e; ++r) {
        float4 t = *(const float4*)(H + (size_t)r * HID + lane * 4);
        a0 += t.x; a1 += t.y; a2 += t.z; a3 += t.w;
    }
    float inv = 1.0f / (float)max(e - s, 1);
    float4 o; o.x = a0 * inv; o.y = a1 * inv; o.z = a2 * inv; o.w = a3 * inv;
    *(float4*)(pooled + (size_t)g * HID + lane * 4) = o;
}

// ---------------------------------------------------------------- SGEMM
// C[M,N] = act( A1[M,K1] @ B1[K1,N] + A2[M,K2] @ B2[K2,N] + bias[N] )
// BM=64 rows per block, BN_ = full N (grid.y == 1) so each block exclusively
// owns its A rows -> C may alias A1 (in-place) safely.
// 256 threads. BN_=256: 8x8 microtile; BN_=128: 4x8 microtile.
#define BM_ 64
#define BK_ 16

template <int BN_>
__launch_bounds__(256)
__global__ void gemm2_k(const float* __restrict__ A1, const float* __restrict__ B1, int K1,
                        const float* __restrict__ A2, const float* __restrict__ B2, int K2,
                        const float* __restrict__ bias, float* __restrict__ C,
                        int M, int N, int do_relu) {
    constexpr int TCOLS = BN_ / 8;        // threads along N
    constexpr int TROWS = 256 / TCOLS;    // threads along M
    constexpr int TM = BM_ / TROWS;       // rows per thread (8 or 4)
    __shared__ float As[BK_][BM_ + 4];
    __shared__ float Bs[BK_][BN_ + 4];
    int tid = threadIdx.x;
    int row0 = blockIdx.x * BM_;
    int col0 = blockIdx.y * BN_;
    int tx = tid % TCOLS, ty = tid / TCOLS;

    float acc[TM][8];
    #pragma unroll
    for (int i = 0; i < TM; ++i)
        #pragma unroll
        for (int j = 0; j < 8; ++j) acc[i][j] = 0.f;

    int ar = tid >> 2;         // 0..63 A row within tile
    int ak = (tid & 3) * 4;    // 0,4,8,12

    int KT = K1 + K2;
    for (int kt = 0; kt < KT; kt += BK_) {
        const float* Ab; const float* Bb; int kk; int Ks;
        if (kt < K1) { Ab = A1; Bb = B1; kk = kt; Ks = K1; }
        else         { Ab = A2; Bb = B2; kk = kt - K1; Ks = K2; }

        {   // A tile: 64x16 floats, one float4 per thread, transposed into LDS
            int r = row0 + ar;
            int rc = min(r, M - 1);
            float4 v = *(const float4*)(Ab + (size_t)rc * Ks + kk + ak);
            As[ak + 0][ar] = v.x;
            As[ak + 1][ar] = v.y;
            As[ak + 2][ar] = v.z;
            As[ak + 3][ar] = v.w;
        }
        {   // B tile: 16 x BN_ floats, BN_/64 float4 per thread
            #pragma unroll
            for (int h = 0; h < BN_ / 64; ++h) {
                int idx = h * 256 + tid;
                int kr = idx / (BN_ / 4);
                int c4 = idx % (BN_ / 4);
                float4 v = *(const float4*)(Bb + (size_t)(kk + kr) * N + col0 + c4 * 4);
                *(float4*)&Bs[kr][c4 * 4] = v;
            }
        }
        __syncthreads();

        #pragma unroll
        for (int k = 0; k < BK_; ++k) {
            float a[TM], b[8];
            #pragma unroll
            for (int v = 0; v < TM / 4; ++v)
                *(float4*)&a[v * 4] = *(const float4*)&As[k][ty * TM + v * 4];
            *(float4*)&b[0] = *(const float4*)&Bs[k][tx * 8];
            *(float4*)&b[4] = *(const float4*)&Bs[k][tx * 8 + 4];
            #pragma unroll
            for (int i = 0; i < TM; ++i)
                #pragma unroll
                for (int j = 0; j < 8; ++j) acc[i][j] = fmaf(a[i], b[j], acc[i][j]);
        }
        __syncthreads();
    }

    // epilogue (runs after all A reads by this block; C may alias A1)
    float bv[8];
    #pragma unroll
    for (int j = 0; j < 8; ++j) bv[j] = bias[col0 + tx * 8 + j];
    #pragma unroll
    for (int i = 0; i < TM; ++i) {
        int r = row0 + ty * TM + i;
        if (r < M) {
            float* cp = C + (size_t)r * N + col0 + tx * 8;
            float o[8];
            #pragma unroll
            for (int j = 0; j < 8; ++j) {
                float v = acc[i][j] + bv[j];
                o[j] = do_relu ? fmaxf(v, 0.f) : v;
            }
            *(float4*)(cp + 0) = *(float4*)&o[0];
            *(float4*)(cp + 4) = *(float4*)&o[4];
        }
    }
}

// ---------------------------------------------------------------- launcher
extern "C" void kernel_launch(void* const* d_in, const int* in_sizes, int n_in,
                              void* d_out, int out_size, void* d_ws, size_t ws_size,
                              hipStream_t stream) {
    const float* x    = (const float*)d_in[0];
    const int*   ei   = (const int*)d_in[1];
    const int*   batch= (const int*)d_in[2];
    const float* W1l  = (const float*)d_in[3];
    const float* b1   = (const float*)d_in[4];
    const float* W1r  = (const float*)d_in[5];
    const float* W2l  = (const float*)d_in[6];
    const float* b2   = (const float*)d_in[7];
    const float* W2r  = (const float*)d_in[8];
    const float* W3   = (const float*)d_in[9];
    const float* b3   = (const float*)d_in[10];
    const float* W4   = (const float*)d_in[11];
    const float* b4   = (const float*)d_in[12];
    float* out = (float*)d_out;

    const int N = N_NODES, E = N_EDGES, G = N_GRAPHS;
    const int* src = ei;
    const int* dst = ei + E;

    // workspace layout (256B aligned). Total ~217 MB.
    char* ws = (char*)d_ws;
    size_t off = 0;
    auto alloc = [&](size_t bytes) -> char* {
        off = (off + 255) & ~(size_t)255;
        char* p = ws + off;
        off += bytes;
        return p;
    };
    int* deg     = (int*)alloc((size_t)N * 4);
    int* cursor  = (int*)alloc((size_t)N * 4);
    int* gcnt    = (int*)alloc((size_t)G * 4);
    size_t zero_span = (size_t)((char*)(gcnt + G) - (char*)deg);
    int* row_ofs = (int*)alloc((size_t)(N + 1) * 4);
    int* gofs    = (int*)alloc((size_t)(G + 1) * 4);
    int* csr     = (int*)alloc((size_t)E * 4);
    // bufA: mean1 [N,128] -> mean2 [N,256] -> h2 [N,256] (in-place gemm2)
    float* bufA  = (float*)alloc((size_t)N * HID * 4);
    // bufB: h1 [N,256]
    float* bufB  = (float*)alloc((size_t)N * HID * 4);
    float* pooled= (float*)alloc((size_t)G * HID * 4);
    float* hidden= (float*)alloc((size_t)G * HID * 4);
    (void)ws_size;

    hipMemsetAsync(deg, 0, zero_span, stream);

    count_edges_k<<<(E + 255) / 256, 256, 0, stream>>>(dst, deg, E);
    count_batch_k<<<(N + 255) / 256, 256, 0, stream>>>(batch, gcnt, N);
    ex_scan_k<<<1, 256, 0, stream>>>(deg, row_ofs, N);
    ex_scan_k<<<1, 256, 0, stream>>>(gcnt, gofs, G);
    fill_csr_k<<<(E + 255) / 256, 256, 0, stream>>>(src, dst, row_ofs, cursor, csr, E);

    const int MB1 = (N + BM_ - 1) / BM_;

    // layer 1: mean-agg(x) -> bufA [N,128]; bufB = relu([bufA|x] @ [W1l;W1r] + b1)
    agg_mean_k<IN_CH><<<(N + 3) / 4, 256, 0, stream>>>(x, row_ofs, csr, bufA, N);
    gemm2_k<HID><<<dim3(MB1, 1), 256, 0, stream>>>(
        bufA, W1l, IN_CH, x, W1r, IN_CH, b1, bufB, N, HID, 1);

    // layer 2: mean-agg(bufB) -> bufA [N,256]; bufA = relu([bufA|bufB] @ [W2l;W2r] + b2)  (in-place)
    agg_mean_k<HID><<<(N + 3) / 4, 256, 0, stream>>>(bufB, row_ofs, csr, bufA, N);
    gemm2_k<HID><<<dim3(MB1, 1), 256, 0, stream>>>(
        bufA, W2l, HID, bufB, W2r, HID, b2, bufA, N, HID, 1);

    // global mean pool over bufA
    pool_mean_k<<<(G + 3) / 4, 256, 0, stream>>>(bufA, gofs, pooled, G);

    // MLP head
    gemm2_k<HID><<<dim3(G / BM_, 1), 256, 0, stream>>>(
        pooled, W3, HID, pooled, W3, 0, b3, hidden, G, HID, 1);
    gemm2_k<OUT_CH><<<dim3(G / BM_, 1), 256, 0, stream>>>(
        hidden, W4, HID, hidden, W4, 0, b4, out, G, OUT_CH, 0);
}

// Round 3
// 1278.187 us; speedup vs baseline: 1.3101x; 1.3101x over previous
//
#include <hip/hip_runtime.h>

#define N_NODES 100000
#define N_EDGES 1600000
#define IN_CH 128
#define HID 256
#define OUT_CH 128
#define N_GRAPHS 2048

// ---------------------------------------------------------------- CSR build
__global__ void count_edges_k(const int* __restrict__ dst, int* __restrict__ deg, int E) {
    int e = blockIdx.x * blockDim.x + threadIdx.x;
    if (e < E) atomicAdd(&deg[dst[e]], 1);
}

// ---------------------------------------------------------------- hierarchical exclusive scan
// tile = 256 threads * 8 items = 2048 elements per block
#define SCAN_ITEMS 8
#define SCAN_TILE (256 * SCAN_ITEMS)

__global__ void scan1_k(const int* __restrict__ in, int* __restrict__ out,
                        int* __restrict__ bsums, int n) {
    __shared__ int wsum[4];
    int base = blockIdx.x * SCAN_TILE + (int)threadIdx.x * SCAN_ITEMS;
    int v[SCAN_ITEMS];
    int s = 0;
    #pragma unroll
    for (int i = 0; i < SCAN_ITEMS; ++i) {
        v[i] = (base + i < n) ? in[base + i] : 0;
        s += v[i];
    }
    int lane = threadIdx.x & 63, wid = threadIdx.x >> 6;
    int incl = s;
    #pragma unroll
    for (int off = 1; off < 64; off <<= 1) {
        int t = __shfl_up(incl, off, 64);
        if (lane >= off) incl += t;
    }
    if (lane == 63) wsum[wid] = incl;
    __syncthreads();
    int wprefix = 0;
    #pragma unroll
    for (int w = 0; w < 4; ++w)
        if (w < wid) wprefix += wsum[w];
    int run = wprefix + incl - s;  // exclusive prefix of this thread's first item
    #pragma unroll
    for (int i = 0; i < SCAN_ITEMS; ++i) {
        if (base + i < n) out[base + i] = run;
        run += v[i];
    }
    if (threadIdx.x == 255) bsums[blockIdx.x] = wprefix + incl;  // block total
}

// single-block exclusive scan of nb (<=256) block sums; writes grand total to *total
__global__ void scan2_k(int* __restrict__ bsums, int nb, int* __restrict__ total) {
    __shared__ int wsum[4];
    int v = ((int)threadIdx.x < nb) ? bsums[threadIdx.x] : 0;
    int lane = threadIdx.x & 63, wid = threadIdx.x >> 6;
    int incl = v;
    #pragma unroll
    for (int off = 1; off < 64; off <<= 1) {
        int t = __shfl_up(incl, off, 64);
        if (lane >= off) incl += t;
    }
    if (lane == 63) wsum[wid] = incl;
    __syncthreads();
    int wprefix = 0;
    #pragma unroll
    for (int w = 0; w < 4; ++w)
        if (w < wid) wprefix += wsum[w];
    if ((int)threadIdx.x < nb) bsums[threadIdx.x] = wprefix + incl - v;
    if (threadIdx.x == 255) *total = wprefix + incl;
}

__global__ void scan3_k(int* __restrict__ out, const int* __restrict__ bsums, int n) {
    int add = bsums[blockIdx.x];
    int base = blockIdx.x * SCAN_TILE + (int)threadIdx.x * SCAN_ITEMS;
    #pragma unroll
    for (int i = 0; i < SCAN_ITEMS; ++i)
        if (base + i < n) out[base + i] += add;
}

// gofs[g] = lower_bound(batch, g)  (batch sorted); gofs[G] = n
__global__ void gofs_search_k(const int* __restrict__ batch, int* __restrict__ gofs,
                              int n, int G) {
    int g = blockIdx.x * blockDim.x + threadIdx.x;
    if (g > G) return;
    if (g == G) { gofs[G] = n; return; }
    int lo = 0, hi = n;
    while (lo < hi) {
        int mid = (lo + hi) >> 1;
        if (batch[mid] < g) lo = mid + 1; else hi = mid;
    }
    gofs[g] = lo;
}

__global__ void fill_csr_k(const int* __restrict__ src, const int* __restrict__ dst,
                           const int* __restrict__ row_ofs, int* __restrict__ cursor,
                           int* __restrict__ csr, int E) {
    int e = blockIdx.x * blockDim.x + threadIdx.x;
    if (e >= E) return;
    int d = dst[e];
    int pos = atomicAdd(&cursor[d], 1);
    csr[row_ofs[d] + pos] = src[e];
}

// ---------------------------------------------------------------- mean aggregation
// one wave per node; lane owns C/64 contiguous channels
template <int C>
__global__ void agg_mean_k(const float* __restrict__ X, const int* __restrict__ row_ofs,
                           const int* __restrict__ csr, float* __restrict__ out, int n) {
    int w = (int)((blockIdx.x * blockDim.x + threadIdx.x) >> 6);
    int lane = threadIdx.x & 63;
    if (w >= n) return;
    constexpr int V = C / 64;  // 2 or 4
    float acc[V];
    #pragma unroll
    for (int v = 0; v < V; ++v) acc[v] = 0.f;
    int s = row_ofs[w], e = row_ofs[w + 1];
    for (int j = s; j < e; ++j) {
        const float* row = X + (size_t)csr[j] * C + lane * V;
        if (V == 2) {
            float2 t = *(const float2*)row;
            acc[0] += t.x; acc[1] += t.y;
        } else {
            float4 t = *(const float4*)row;
            acc[0] += t.x; acc[1] += t.y; acc[2] += t.z; acc[3] += t.w;
        }
    }
    float inv = 1.0f / (float)max(e - s, 1);
    float* op = out + (size_t)w * C + lane * V;
    if (V == 2) {
        float2 t; t.x = acc[0] * inv; t.y = acc[1] * inv;
        *(float2*)op = t;
    } else {
        float4 t; t.x = acc[0] * inv; t.y = acc[1] * inv; t.z = acc[2] * inv; t.w = acc[3] * inv;
        *(float4*)op = t;
    }
}

// one wave per graph (batch is sorted -> contiguous row ranges)
__global__ void pool_mean_k(const float* __restrict__ H, const int* __restrict__ gofs,
                            float* __restrict__ pooled, int G) {
    int g = (int)((blockIdx.x * blockDim.x + threadIdx.x) >> 6);
    int lane = threadIdx.x & 63;
    if (g >= G) return;
    int s = gofs[g], e = gofs[g + 1];
    float a0 = 0.f, a1 = 0.f, a2 = 0.f, a3 = 0.f;
    for (int r = s; r < e; ++r) {
        float4 t = *(const float4*)(H + (size_t)r * HID + lane * 4);
        a0 += t.x; a1 += t.y; a2 += t.z; a3 += t.w;
    }
    float inv = 1.0f / (float)max(e - s, 1);
    float4 o; o.x = a0 * inv; o.y = a1 * inv; o.z = a2 * inv; o.w = a3 * inv;
    *(float4*)(pooled + (size_t)g * HID + lane * 4) = o;
}

// ---------------------------------------------------------------- SGEMM
// C[M,N] = act( A1[M,K1] @ B1[K1,N] + A2[M,K2] @ B2[K2,N] + bias[N] )
// BM=64 rows per block, BN_ = full N (grid.y == 1) so each block exclusively
// owns its A rows -> C may alias A1 (in-place) safely.
// 256 threads. BN_=256: 8x8 microtile; BN_=128: 4x8 microtile.
#define BM_ 64
#define BK_ 16

template <int BN_>
__launch_bounds__(256)
__global__ void gemm2_k(const float* __restrict__ A1, const float* __restrict__ B1, int K1,
                        const float* __restrict__ A2, const float* __restrict__ B2, int K2,
                        const float* __restrict__ bias, float* __restrict__ C,
                        int M, int N, int do_relu) {
    constexpr int TCOLS = BN_ / 8;        // threads along N
    constexpr int TROWS = 256 / TCOLS;    // threads along M
    constexpr int TM = BM_ / TROWS;       // rows per thread (8 or 4)
    __shared__ float As[BK_][BM_ + 4];
    __shared__ float Bs[BK_][BN_ + 4];
    int tid = threadIdx.x;
    int row0 = blockIdx.x * BM_;
    int col0 = blockIdx.y * BN_;
    int tx = tid % TCOLS, ty = tid / TCOLS;

    float acc[TM][8];
    #pragma unroll
    for (int i = 0; i < TM; ++i)
        #pragma unroll
        for (int j = 0; j < 8; ++j) acc[i][j] = 0.f;

    int ar = tid >> 2;         // 0..63 A row within tile
    int ak = (tid & 3) * 4;    // 0,4,8,12

    int KT = K1 + K2;
    for (int kt = 0; kt < KT; kt += BK_) {
        const float* Ab; const float* Bb; int kk; int Ks;
        if (kt < K1) { Ab = A1; Bb = B1; kk = kt; Ks = K1; }
        else         { Ab = A2; Bb = B2; kk = kt - K1; Ks = K2; }

        {   // A tile: 64x16 floats, one float4 per thread, transposed into LDS
            int r = row0 + ar;
            int rc = min(r, M - 1);
            float4 v = *(const float4*)(Ab + (size_t)rc * Ks + kk + ak);
            As[ak + 0][ar] = v.x;
            As[ak + 1][ar] = v.y;
            As[ak + 2][ar] = v.z;
            As[ak + 3][ar] = v.w;
        }
        {   // B tile: 16 x BN_ floats, BN_/64 float4 per thread
            #pragma unroll
            for (int h = 0; h < BN_ / 64; ++h) {
                int idx = h * 256 + tid;
                int kr = idx / (BN_ / 4);
                int c4 = idx % (BN_ / 4);
                float4 v = *(const float4*)(Bb + (size_t)(kk + kr) * N + col0 + c4 * 4);
                *(float4*)&Bs[kr][c4 * 4] = v;
            }
        }
        __syncthreads();

        #pragma unroll
        for (int k = 0; k < BK_; ++k) {
            float a[TM], b[8];
            #pragma unroll
            for (int v = 0; v < TM / 4; ++v)
                *(float4*)&a[v * 4] = *(const float4*)&As[k][ty * TM + v * 4];
            *(float4*)&b[0] = *(const float4*)&Bs[k][tx * 8];
            *(float4*)&b[4] = *(const float4*)&Bs[k][tx * 8 + 4];
            #pragma unroll
            for (int i = 0; i < TM; ++i)
                #pragma unroll
                for (int j = 0; j < 8; ++j) acc[i][j] = fmaf(a[i], b[j], acc[i][j]);
        }
        __syncthreads();
    }

    // epilogue (runs after all A reads by this block; C may alias A1)
    float bv[8];
    #pragma unroll
    for (int j = 0; j < 8; ++j) bv[j] = bias[col0 + tx * 8 + j];
    #pragma unroll
    for (int i = 0; i < TM; ++i) {
        int r = row0 + ty * TM + i;
        if (r < M) {
            float* cp = C + (size_t)r * N + col0 + tx * 8;
            float o[8];
            #pragma unroll
            for (int j = 0; j < 8; ++j) {
                float v = acc[i][j] + bv[j];
                o[j] = do_relu ? fmaxf(v, 0.f) : v;
            }
            *(float4*)(cp + 0) = *(float4*)&o[0];
            *(float4*)(cp + 4) = *(float4*)&o[4];
        }
    }
}

// ---------------------------------------------------------------- launcher
extern "C" void kernel_launch(void* const* d_in, const int* in_sizes, int n_in,
                              void* d_out, int out_size, void* d_ws, size_t ws_size,
                              hipStream_t stream) {
    const float* x    = (const float*)d_in[0];
    const int*   ei   = (const int*)d_in[1];
    const int*   batch= (const int*)d_in[2];
    const float* W1l  = (const float*)d_in[3];
    const float* b1   = (const float*)d_in[4];
    const float* W1r  = (const float*)d_in[5];
    const float* W2l  = (const float*)d_in[6];
    const float* b2   = (const float*)d_in[7];
    const float* W2r  = (const float*)d_in[8];
    const float* W3   = (const float*)d_in[9];
    const float* b3   = (const float*)d_in[10];
    const float* W4   = (const float*)d_in[11];
    const float* b4   = (const float*)d_in[12];
    float* out = (float*)d_out;

    const int N = N_NODES, E = N_EDGES, G = N_GRAPHS;
    const int* src = ei;
    const int* dst = ei + E;

    // workspace layout (256B aligned). Total ~217 MB.
    char* ws = (char*)d_ws;
    size_t off = 0;
    auto alloc = [&](size_t bytes) -> char* {
        off = (off + 255) & ~(size_t)255;
        char* p = ws + off;
        off += bytes;
        return p;
    };
    int* deg     = (int*)alloc((size_t)N * 4);
    int* cursor  = (int*)alloc((size_t)N * 4);
    size_t zero_span = (size_t)((char*)(cursor + N) - (char*)deg);
    int* row_ofs = (int*)alloc((size_t)(N + 1) * 4);
    int* gofs    = (int*)alloc((size_t)(G + 1) * 4);
    int* bsums   = (int*)alloc(256 * 4);
    int* csr     = (int*)alloc((size_t)E * 4);
    // bufA: mean1 [N,128] -> mean2 [N,256] -> h2 [N,256] (in-place gemm2)
    float* bufA  = (float*)alloc((size_t)N * HID * 4);
    // bufB: h1 [N,256]
    float* bufB  = (float*)alloc((size_t)N * HID * 4);
    float* pooled= (float*)alloc((size_t)G * HID * 4);
    float* hidden= (float*)alloc((size_t)G * HID * 4);
    (void)ws_size;

    hipMemsetAsync(deg, 0, zero_span, stream);

    count_edges_k<<<(E + 255) / 256, 256, 0, stream>>>(dst, deg, E);

    const int nb = (N + SCAN_TILE - 1) / SCAN_TILE;   // 49
    scan1_k<<<nb, 256, 0, stream>>>(deg, row_ofs, bsums, N);
    scan2_k<<<1, 256, 0, stream>>>(bsums, nb, row_ofs + N);
    scan3_k<<<nb, 256, 0, stream>>>(row_ofs, bsums, N);

    gofs_search_k<<<(G + 256) / 256, 256, 0, stream>>>(batch, gofs, N, G);

    fill_csr_k<<<(E + 255) / 256, 256, 0, stream>>>(src, dst, row_ofs, cursor, csr, E);

    const int MB1 = (N + BM_ - 1) / BM_;

    // layer 1: mean-agg(x) -> bufA [N,128]; bufB = relu([bufA|x] @ [W1l;W1r] + b1)
    agg_mean_k<IN_CH><<<(N + 3) / 4, 256, 0, stream>>>(x, row_ofs, csr, bufA, N);
    gemm2_k<HID><<<dim3(MB1, 1), 256, 0, stream>>>(
        bufA, W1l, IN_CH, x, W1r, IN_CH, b1, bufB, N, HID, 1);

    // layer 2: mean-agg(bufB) -> bufA [N,256]; bufA = relu([bufA|bufB] @ [W2l;W2r] + b2)  (in-place)
    agg_mean_k<HID><<<(N + 3) / 4, 256, 0, stream>>>(bufB, row_ofs, csr, bufA, N);
    gemm2_k<HID><<<dim3(MB1, 1), 256, 0, stream>>>(
        bufA, W2l, HID, bufB, W2r, HID, b2, bufA, N, HID, 1);

    // global mean pool over bufA
    pool_mean_k<<<(G + 3) / 4, 256, 0, stream>>>(bufA, gofs, pooled, G);

    // MLP head
    gemm2_k<HID><<<dim3(G / BM_, 1), 256, 0, stream>>>(
        pooled, W3, HID, pooled, W3, 0, b3, hidden, G, HID, 1);
    gemm2_k<OUT_CH><<<dim3(G / BM_, 1), 256, 0, stream>>>(
        hidden, W4, HID, hidden, W4, 0, b4, out, G, OUT_CH, 0);
}

// Round 4
// 836.275 us; speedup vs baseline: 2.0024x; 1.5284x over previous
//
#include <hip/hip_runtime.h>

#define N_NODES 100000
#define N_EDGES 1600000
#define IN_CH 128
#define HID 256
#define OUT_CH 128
#define N_GRAPHS 2048

typedef __attribute__((ext_vector_type(8))) short bf16x8;
typedef __attribute__((ext_vector_type(4))) float f32x4;

__device__ inline unsigned short f2b(float f) {  // RNE fp32 -> bf16
    unsigned int u = __builtin_bit_cast(unsigned int, f);
    u = (u + 0x7FFF + ((u >> 16) & 1)) >> 16;
    return (unsigned short)u;
}
__device__ inline float b2f(unsigned short h) {
    unsigned int u = (unsigned int)h << 16;
    return __builtin_bit_cast(float, u);
}

// ---------------------------------------------------------------- CSR build
__global__ void count_edges_k(const int* __restrict__ dst, int* __restrict__ deg, int E) {
    int e = blockIdx.x * blockDim.x + threadIdx.x;
    if (e < E) atomicAdd(&deg[dst[e]], 1);
}

#define SCAN_ITEMS 8
#define SCAN_TILE (256 * SCAN_ITEMS)

__global__ void scan1_k(const int* __restrict__ in, int* __restrict__ out,
                        int* __restrict__ bsums, int n) {
    __shared__ int wsum[4];
    int base = blockIdx.x * SCAN_TILE + (int)threadIdx.x * SCAN_ITEMS;
    int v[SCAN_ITEMS];
    int s = 0;
    #pragma unroll
    for (int i = 0; i < SCAN_ITEMS; ++i) {
        v[i] = (base + i < n) ? in[base + i] : 0;
        s += v[i];
    }
    int lane = threadIdx.x & 63, wid = threadIdx.x >> 6;
    int incl = s;
    #pragma unroll
    for (int off = 1; off < 64; off <<= 1) {
        int t = __shfl_up(incl, off, 64);
        if (lane >= off) incl += t;
    }
    if (lane == 63) wsum[wid] = incl;
    __syncthreads();
    int wprefix = 0;
    #pragma unroll
    for (int w = 0; w < 4; ++w)
        if (w < wid) wprefix += wsum[w];
    int run = wprefix + incl - s;
    #pragma unroll
    for (int i = 0; i < SCAN_ITEMS; ++i) {
        if (base + i < n) out[base + i] = run;
        run += v[i];
    }
    if (threadIdx.x == 255) bsums[blockIdx.x] = wprefix + incl;
}

__global__ void scan2_k(int* __restrict__ bsums, int nb, int* __restrict__ total) {
    __shared__ int wsum[4];
    int v = ((int)threadIdx.x < nb) ? bsums[threadIdx.x] : 0;
    int lane = threadIdx.x & 63, wid = threadIdx.x >> 6;
    int incl = v;
    #pragma unroll
    for (int off = 1; off < 64; off <<= 1) {
        int t = __shfl_up(incl, off, 64);
        if (lane >= off) incl += t;
    }
    if (lane == 63) wsum[wid] = incl;
    __syncthreads();
    int wprefix = 0;
    #pragma unroll
    for (int w = 0; w < 4; ++w)
        if (w < wid) wprefix += wsum[w];
    if ((int)threadIdx.x < nb) bsums[threadIdx.x] = wprefix + incl - v;
    if (threadIdx.x == 255) *total = wprefix + incl;
}

__global__ void scan3_k(int* __restrict__ out, const int* __restrict__ bsums, int n) {
    int add = bsums[blockIdx.x];
    int base = blockIdx.x * SCAN_TILE + (int)threadIdx.x * SCAN_ITEMS;
    #pragma unroll
    for (int i = 0; i < SCAN_ITEMS; ++i)
        if (base + i < n) out[base + i] += add;
}

__global__ void gofs_search_k(const int* __restrict__ batch, int* __restrict__ gofs,
                              int n, int G) {
    int g = blockIdx.x * blockDim.x + threadIdx.x;
    if (g > G) return;
    if (g == G) { gofs[G] = n; return; }
    int lo = 0, hi = n;
    while (lo < hi) {
        int mid = (lo + hi) >> 1;
        if (batch[mid] < g) lo = mid + 1; else hi = mid;
    }
    gofs[g] = lo;
}

__global__ void fill_csr_k(const int* __restrict__ src, const int* __restrict__ dst,
                           const int* __restrict__ row_ofs, int* __restrict__ cursor,
                           int* __restrict__ csr, int E) {
    int e = blockIdx.x * blockDim.x + threadIdx.x;
    if (e >= E) return;
    int d = dst[e];
    int pos = atomicAdd(&cursor[d], 1);
    csr[row_ofs[d] + pos] = src[e];
}

// ---------------------------------------------------------------- converts
// fp32 [K1,N]+[K2,N] -> bf16 transposed concat [N][K1+K2]
__global__ void wt_concat_k(const float* __restrict__ Wl, const float* __restrict__ Wr,
                            unsigned short* __restrict__ out, int K1, int K2, int N) {
    int idx = blockIdx.x * blockDim.x + threadIdx.x;
    int KT = K1 + K2;
    if (idx >= N * KT) return;
    int n = idx / KT, k = idx % KT;
    float v = (k < K1) ? Wl[(size_t)k * N + n] : Wr[(size_t)(k - K1) * N + n];
    out[idx] = f2b(v);
}

__global__ void f2b_mat_k(const float* __restrict__ in, unsigned short* __restrict__ out,
                          size_t n4) {
    size_t i = (size_t)blockIdx.x * blockDim.x + threadIdx.x;
    if (i >= n4) return;
    float4 v = ((const float4*)in)[i];
    ushort4 o;
    o.x = f2b(v.x); o.y = f2b(v.y); o.z = f2b(v.z); o.w = f2b(v.w);
    ((ushort4*)out)[i] = o;
}

// ---------------------------------------------------------------- mean aggregation
// layer 1: fp32 input [N,128] -> bf16 out; one wave per node, lane owns 2 ch
__global__ void agg1_k(const float* __restrict__ X, const int* __restrict__ row_ofs,
                       const int* __restrict__ csr, unsigned short* __restrict__ out, int n) {
    int w = (int)((blockIdx.x * blockDim.x + threadIdx.x) >> 6);
    int lane = threadIdx.x & 63;
    if (w >= n) return;
    float a0 = 0.f, a1 = 0.f;
    int s = row_ofs[w], e = row_ofs[w + 1];
    for (int j = s; j < e; ++j) {
        const float2 t = *(const float2*)(X + (size_t)csr[j] * IN_CH + lane * 2);
        a0 += t.x; a1 += t.y;
    }
    float inv = 1.0f / (float)max(e - s, 1);
    unsigned int p = (unsigned int)f2b(a0 * inv) | ((unsigned int)f2b(a1 * inv) << 16);
    ((unsigned int*)(out + (size_t)w * IN_CH))[lane] = p;
}

// layer 2: bf16 input [N,256] -> bf16 out; lane owns 4 ch
__global__ void agg2_k(const unsigned short* __restrict__ X, const int* __restrict__ row_ofs,
                       const int* __restrict__ csr, unsigned short* __restrict__ out, int n) {
    int w = (int)((blockIdx.x * blockDim.x + threadIdx.x) >> 6);
    int lane = threadIdx.x & 63;
    if (w >= n) return;
    float a0 = 0.f, a1 = 0.f, a2 = 0.f, a3 = 0.f;
    int s = row_ofs[w], e = row_ofs[w + 1];
    for (int j = s; j < e; ++j) {
        ushort4 t = ((const ushort4*)(X + (size_t)csr[j] * HID))[lane];
        a0 += b2f(t.x); a1 += b2f(t.y); a2 += b2f(t.z); a3 += b2f(t.w);
    }
    float inv = 1.0f / (float)max(e - s, 1);
    uint2 p;
    p.x = (unsigned int)f2b(a0 * inv) | ((unsigned int)f2b(a1 * inv) << 16);
    p.y = (unsigned int)f2b(a2 * inv) | ((unsigned int)f2b(a3 * inv) << 16);
    ((uint2*)(out + (size_t)w * HID))[lane] = p;
}

// pool: bf16 input [N,256] -> fp32 pooled [G,256]; one wave per graph
__global__ void pool_mean_k(const unsigned short* __restrict__ H, const int* __restrict__ gofs,
                            float* __restrict__ pooled, int G) {
    int g = (int)((blockIdx.x * blockDim.x + threadIdx.x) >> 6);
    int lane = threadIdx.x & 63;
    if (g >= G) return;
    int s = gofs[g], e = gofs[g + 1];
    float a0 = 0.f, a1 = 0.f, a2 = 0.f, a3 = 0.f;
    for (int r = s; r < e; ++r) {
        ushort4 t = ((const ushort4*)(H + (size_t)r * HID))[lane];
        a0 += b2f(t.x); a1 += b2f(t.y); a2 += b2f(t.z); a3 += b2f(t.w);
    }
    float inv = 1.0f / (float)max(e - s, 1);
    float4 o; o.x = a0 * inv; o.y = a1 * inv; o.z = a2 * inv; o.w = a3 * inv;
    ((float4*)(pooled + (size_t)g * HID))[lane] = o;
}

// ---------------------------------------------------------------- bf16 MFMA GEMM
// C[M,Nfull] = act( [A1|A2][M,K1+K2] @ Bt[Nfull,K1+K2]^T + bias )
// 128x128 tile, 256 threads = 4 waves in 2x2, each wave 64x64 (4x4 MFMA frags), BK=32.
__launch_bounds__(256)
__global__ void mfma_gemm_k(const unsigned short* __restrict__ A1, int K1,
                            const unsigned short* __restrict__ A2, int K2,
                            const unsigned short* __restrict__ Bt,
                            const float* __restrict__ bias, int M, int Nfull,
                            void* __restrict__ Cptr, int c_bf16, int do_relu) {
    __shared__ short ldsA[128 * 32];
    __shared__ short ldsB[128 * 32];
    int tid = threadIdx.x, lane = tid & 63;
    int wid = tid >> 6, wm = wid >> 1, wn = wid & 1;
    int row0 = blockIdx.x * 128, col0 = blockIdx.y * 128;
    int q = lane >> 4, l15 = lane & 15;
    int KT = K1 + K2;

    f32x4 acc[4][4] = {};

    for (int kt = 0; kt < KT; kt += 32) {
        const unsigned short* Asrc; int kk, Ks;
        if (kt < K1) { Asrc = A1; kk = kt; Ks = K1; }
        else         { Asrc = A2; kk = kt - K1; Ks = K2; }
        #pragma unroll
        for (int h = 0; h < 2; ++h) {          // A tile [128 rows][32 k] bf16
            int c = tid + h * 256;             // 0..511 chunk of 8 bf16
            int r = c >> 2, c8 = (c & 3) * 8;
            int gr = min(row0 + r, M - 1);
            *(uint4*)&ldsA[r * 32 + c8] = *(const uint4*)&Asrc[(size_t)gr * Ks + kk + c8];
        }
        #pragma unroll
        for (int h = 0; h < 2; ++h) {          // B tile [128 n][32 k] bf16 (Bt rows)
            int c = tid + h * 256;
            int r = c >> 2, c8 = (c & 3) * 8;
            *(uint4*)&ldsB[r * 32 + c8] = *(const uint4*)&Bt[(size_t)(col0 + r) * KT + kt + c8];
        }
        __syncthreads();

        bf16x8 af[4], bfr[4];
        #pragma unroll
        for (int i = 0; i < 4; ++i)
            af[i] = *(const bf16x8*)&ldsA[(wm * 64 + i * 16 + l15) * 32 + q * 8];
        #pragma unroll
        for (int j = 0; j < 4; ++j)
            bfr[j] = *(const bf16x8*)&ldsB[(wn * 64 + j * 16 + l15) * 32 + q * 8];
        #pragma unroll
        for (int i = 0; i < 4; ++i)
            #pragma unroll
            for (int j = 0; j < 4; ++j)
                acc[i][j] = __builtin_amdgcn_mfma_f32_16x16x32_bf16(af[i], bfr[j], acc[i][j], 0, 0, 0);
        __syncthreads();
    }

    // epilogue: D layout col=lane&15, row=quad*4+reg
    #pragma unroll
    for (int i = 0; i < 4; ++i) {
        #pragma unroll
        for (int reg = 0; reg < 4; ++reg) {
            int r = row0 + wm * 64 + i * 16 + q * 4 + reg;
            if (r < M) {
                #pragma unroll
                for (int j = 0; j < 4; ++j) {
                    int cc = col0 + wn * 64 + j * 16 + l15;
                    float v = acc[i][j][reg] + bias[cc];
                    if (do_relu) v = fmaxf(v, 0.f);
                    if (c_bf16) ((unsigned short*)Cptr)[(size_t)r * Nfull + cc] = f2b(v);
                    else        ((float*)Cptr)[(size_t)r * Nfull + cc] = v;
                }
            }
        }
    }
}

// ---------------------------------------------------------------- fp32 GEMM (head only)
#define BM_ 64
#define BK_ 16

template <int BN_>
__launch_bounds__(256)
__global__ void gemm2_k(const float* __restrict__ A1, const float* __restrict__ B1, int K1,
                        const float* __restrict__ bias, float* __restrict__ C,
                        int M, int N, int do_relu) {
    constexpr int TCOLS = BN_ / 8;
    constexpr int TROWS = 256 / TCOLS;
    constexpr int TM = BM_ / TROWS;
    __shared__ float As[BK_][BM_ + 4];
    __shared__ float Bs[BK_][BN_ + 4];
    int tid = threadIdx.x;
    int row0 = blockIdx.x * BM_;
    int col0 = blockIdx.y * BN_;
    int tx = tid % TCOLS, ty = tid / TCOLS;

    float acc[TM][8];
    #pragma unroll
    for (int i = 0; i < TM; ++i)
        #pragma unroll
        for (int j = 0; j < 8; ++j) acc[i][j] = 0.f;

    int ar = tid >> 2;
    int ak = (tid & 3) * 4;

    for (int kt = 0; kt < K1; kt += BK_) {
        {
            int r = row0 + ar;
            int rc = min(r, M - 1);
            float4 v = *(const float4*)(A1 + (size_t)rc * K1 + kt + ak);
            As[ak + 0][ar] = v.x;
            As[ak + 1][ar] = v.y;
            As[ak + 2][ar] = v.z;
            As[ak + 3][ar] = v.w;
        }
        {
            #pragma unroll
            for (int h = 0; h < BN_ / 64; ++h) {
                int idx = h * 256 + tid;
                int kr = idx / (BN_ / 4);
                int c4 = idx % (BN_ / 4);
                float4 v = *(const float4*)(B1 + (size_t)(kt + kr) * N + col0 + c4 * 4);
                *(float4*)&Bs[kr][c4 * 4] = v;
            }
        }
        __syncthreads();

        #pragma unroll
        for (int k = 0; k < BK_; ++k) {
            float a[TM], b[8];
            #pragma unroll
            for (int v = 0; v < TM / 4; ++v)
                *(float4*)&a[v * 4] = *(const float4*)&As[k][ty * TM + v * 4];
            *(float4*)&b[0] = *(const float4*)&Bs[k][tx * 8];
            *(float4*)&b[4] = *(const float4*)&Bs[k][tx * 8 + 4];
            #pragma unroll
            for (int i = 0; i < TM; ++i)
                #pragma unroll
                for (int j = 0; j < 8; ++j) acc[i][j] = fmaf(a[i], b[j], acc[i][j]);
        }
        __syncthreads();
    }

    float bv[8];
    #pragma unroll
    for (int j = 0; j < 8; ++j) bv[j] = bias[col0 + tx * 8 + j];
    #pragma unroll
    for (int i = 0; i < TM; ++i) {
        int r = row0 + ty * TM + i;
        if (r < M) {
            float* cp = C + (size_t)r * N + col0 + tx * 8;
            float o[8];
            #pragma unroll
            for (int j = 0; j < 8; ++j) {
                float v = acc[i][j] + bv[j];
                o[j] = do_relu ? fmaxf(v, 0.f) : v;
            }
            *(float4*)(cp + 0) = *(float4*)&o[0];
            *(float4*)(cp + 4) = *(float4*)&o[4];
        }
    }
}

// ---------------------------------------------------------------- launcher
extern "C" void kernel_launch(void* const* d_in, const int* in_sizes, int n_in,
                              void* d_out, int out_size, void* d_ws, size_t ws_size,
                              hipStream_t stream) {
    const float* x    = (const float*)d_in[0];
    const int*   ei   = (const int*)d_in[1];
    const int*   batch= (const int*)d_in[2];
    const float* W1l  = (const float*)d_in[3];
    const float* b1   = (const float*)d_in[4];
    const float* W1r  = (const float*)d_in[5];
    const float* W2l  = (const float*)d_in[6];
    const float* b2   = (const float*)d_in[7];
    const float* W2r  = (const float*)d_in[8];
    const float* W3   = (const float*)d_in[9];
    const float* b3   = (const float*)d_in[10];
    const float* W4   = (const float*)d_in[11];
    const float* b4   = (const float*)d_in[12];
    float* out = (float*)d_out;

    const int N = N_NODES, E = N_EDGES, G = N_GRAPHS;
    const int* src = ei;
    const int* dst = ei + E;

    char* ws = (char*)d_ws;
    size_t off = 0;
    auto alloc = [&](size_t bytes) -> char* {
        off = (off + 255) & ~(size_t)255;
        char* p = ws + off;
        off += bytes;
        return p;
    };
    int* deg     = (int*)alloc((size_t)N * 4);
    int* cursor  = (int*)alloc((size_t)N * 4);
    size_t zero_span = (size_t)((char*)(cursor + N) - (char*)deg);
    int* row_ofs = (int*)alloc((size_t)(N + 1) * 4);
    int* gofs    = (int*)alloc((size_t)(G + 1) * 4);
    int* bsums   = (int*)alloc(256 * 4);
    int* csr     = (int*)alloc((size_t)E * 4);
    // bf16 buffers. xb+mean1 are contiguous (each N*128 ushort, 256B-multiple)
    // and both dead after gemm1 -> h2 [N,256] reuses their combined span.
    unsigned short* xb    = (unsigned short*)alloc((size_t)N * IN_CH * 2);
    unsigned short* mean1 = (unsigned short*)alloc((size_t)N * IN_CH * 2);
    unsigned short* h1    = (unsigned short*)alloc((size_t)N * HID * 2);
    unsigned short* mean2 = (unsigned short*)alloc((size_t)N * HID * 2);
    unsigned short* h2    = xb;  // reuse
    unsigned short* W1T   = (unsigned short*)alloc((size_t)HID * (IN_CH + IN_CH) * 2);
    unsigned short* W2T   = (unsigned short*)alloc((size_t)HID * (HID + HID) * 2);
    float* pooled = (float*)alloc((size_t)G * HID * 4);
    float* hidden = (float*)alloc((size_t)G * HID * 4);
    (void)ws_size;

    hipMemsetAsync(deg, 0, zero_span, stream);

    count_edges_k<<<(E + 255) / 256, 256, 0, stream>>>(dst, deg, E);

    const int nb = (N + SCAN_TILE - 1) / SCAN_TILE;
    scan1_k<<<nb, 256, 0, stream>>>(deg, row_ofs, bsums, N);
    scan2_k<<<1, 256, 0, stream>>>(bsums, nb, row_ofs + N);
    scan3_k<<<nb, 256, 0, stream>>>(row_ofs, bsums, N);

    gofs_search_k<<<(G + 256) / 256, 256, 0, stream>>>(batch, gofs, N, G);

    fill_csr_k<<<(E + 255) / 256, 256, 0, stream>>>(src, dst, row_ofs, cursor, csr, E);

    // weight converts (tiny)
    wt_concat_k<<<(HID * 2 * IN_CH + 255) / 256, 256, 0, stream>>>(W1l, W1r, W1T, IN_CH, IN_CH, HID);
    wt_concat_k<<<(HID * 2 * HID + 255) / 256, 256, 0, stream>>>(W2l, W2r, W2T, HID, HID, HID);
    f2b_mat_k<<<((N * IN_CH / 4) + 255) / 256, 256, 0, stream>>>(x, xb, (size_t)N * IN_CH / 4);

    const int MB = (N + 127) / 128;  // 782

    // layer 1: mean1 = bf16 mean-agg(x); h1 = relu([mean1|xb] @ W1T^T + b1)
    agg1_k<<<(N + 3) / 4, 256, 0, stream>>>(x, row_ofs, csr, mean1, N);
    mfma_gemm_k<<<dim3(MB, HID / 128), 256, 0, stream>>>(
        mean1, IN_CH, xb, IN_CH, W1T, b1, N, HID, h1, 1, 1);

    // layer 2: mean2 = bf16 mean-agg(h1); h2 = relu([mean2|h1] @ W2T^T + b2)
    agg2_k<<<(N + 3) / 4, 256, 0, stream>>>(h1, row_ofs, csr, mean2, N);
    mfma_gemm_k<<<dim3(MB, HID / 128), 256, 0, stream>>>(
        mean2, HID, h1, HID, W2T, b2, N, HID, h2, 1, 1);

    // global mean pool (bf16 in, fp32 out)
    pool_mean_k<<<(G + 3) / 4, 256, 0, stream>>>(h2, gofs, pooled, G);

    // MLP head (fp32)
    gemm2_k<HID><<<dim3(G / BM_, 1), 256, 0, stream>>>(
        pooled, W3, HID, b3, hidden, G, HID, 1);
    gemm2_k<OUT_CH><<<dim3(G / BM_, 1), 256, 0, stream>>>(
        hidden, W4, HID, b4, out, G, OUT_CH, 0);
}

// Round 5
// 672.696 us; speedup vs baseline: 2.4893x; 1.2432x over previous
//
#include <hip/hip_runtime.h>

#define N_NODES 100000
#define N_EDGES 1600000
#define IN_CH 128
#define HID 256
#define OUT_CH 128
#define N_GRAPHS 2048

typedef __attribute__((ext_vector_type(8))) short bf16x8;
typedef __attribute__((ext_vector_type(4))) float f32x4;

__device__ inline unsigned short f2b(float f) {  // RNE fp32 -> bf16
    unsigned int u = __builtin_bit_cast(unsigned int, f);
    u = (u + 0x7FFF + ((u >> 16) & 1)) >> 16;
    return (unsigned short)u;
}
__device__ inline float b2f(unsigned short h) {
    unsigned int u = (unsigned int)h << 16;
    return __builtin_bit_cast(float, u);
}

// ---------------------------------------------------------------- CSR build
__global__ void count_edges_k(const int* __restrict__ dst, int* __restrict__ deg, int E) {
    int e = blockIdx.x * blockDim.x + threadIdx.x;
    if (e < E) atomicAdd(&deg[dst[e]], 1);
}

#define SCAN_ITEMS 8
#define SCAN_TILE (256 * SCAN_ITEMS)

__global__ void scan1_k(const int* __restrict__ in, int* __restrict__ out,
                        int* __restrict__ bsums, int n) {
    __shared__ int wsum[4];
    int base = blockIdx.x * SCAN_TILE + (int)threadIdx.x * SCAN_ITEMS;
    int v[SCAN_ITEMS];
    int s = 0;
    #pragma unroll
    for (int i = 0; i < SCAN_ITEMS; ++i) {
        v[i] = (base + i < n) ? in[base + i] : 0;
        s += v[i];
    }
    int lane = threadIdx.x & 63, wid = threadIdx.x >> 6;
    int incl = s;
    #pragma unroll
    for (int off = 1; off < 64; off <<= 1) {
        int t = __shfl_up(incl, off, 64);
        if (lane >= off) incl += t;
    }
    if (lane == 63) wsum[wid] = incl;
    __syncthreads();
    int wprefix = 0;
    #pragma unroll
    for (int w = 0; w < 4; ++w)
        if (w < wid) wprefix += wsum[w];
    int run = wprefix + incl - s;
    #pragma unroll
    for (int i = 0; i < SCAN_ITEMS; ++i) {
        if (base + i < n) out[base + i] = run;
        run += v[i];
    }
    if (threadIdx.x == 255) bsums[blockIdx.x] = wprefix + incl;
}

__global__ void scan2_k(int* __restrict__ bsums, int nb, int* __restrict__ total) {
    __shared__ int wsum[4];
    int v = ((int)threadIdx.x < nb) ? bsums[threadIdx.x] : 0;
    int lane = threadIdx.x & 63, wid = threadIdx.x >> 6;
    int incl = v;
    #pragma unroll
    for (int off = 1; off < 64; off <<= 1) {
        int t = __shfl_up(incl, off, 64);
        if (lane >= off) incl += t;
    }
    if (lane == 63) wsum[wid] = incl;
    __syncthreads();
    int wprefix = 0;
    #pragma unroll
    for (int w = 0; w < 4; ++w)
        if (w < wid) wprefix += wsum[w];
    if ((int)threadIdx.x < nb) bsums[threadIdx.x] = wprefix + incl - v;
    if (threadIdx.x == 255) *total = wprefix + incl;
}

__global__ void scan3_k(int* __restrict__ out, const int* __restrict__ bsums, int n) {
    int add = bsums[blockIdx.x];
    int base = blockIdx.x * SCAN_TILE + (int)threadIdx.x * SCAN_ITEMS;
    #pragma unroll
    for (int i = 0; i < SCAN_ITEMS; ++i)
        if (base + i < n) out[base + i] += add;
}

__global__ void gofs_search_k(const int* __restrict__ batch, int* __restrict__ gofs,
                              int n, int G) {
    int g = blockIdx.x * blockDim.x + threadIdx.x;
    if (g > G) return;
    if (g == G) { gofs[G] = n; return; }
    int lo = 0, hi = n;
    while (lo < hi) {
        int mid = (lo + hi) >> 1;
        if (batch[mid] < g) lo = mid + 1; else hi = mid;
    }
    gofs[g] = lo;
}

__global__ void fill_csr_k(const int* __restrict__ src, const int* __restrict__ dst,
                           const int* __restrict__ row_ofs, int* __restrict__ cursor,
                           int* __restrict__ csr, int E) {
    int e = blockIdx.x * blockDim.x + threadIdx.x;
    if (e >= E) return;
    int d = dst[e];
    int pos = atomicAdd(&cursor[d], 1);
    csr[row_ofs[d] + pos] = src[e];
}

// ---------------------------------------------------------------- converts
__global__ void wt_concat_k(const float* __restrict__ Wl, const float* __restrict__ Wr,
                            unsigned short* __restrict__ out, int K1, int K2, int N) {
    int idx = blockIdx.x * blockDim.x + threadIdx.x;
    int KT = K1 + K2;
    if (idx >= N * KT) return;
    int n = idx / KT, k = idx % KT;
    float v = (k < K1) ? Wl[(size_t)k * N + n] : Wr[(size_t)(k - K1) * N + n];
    out[idx] = f2b(v);
}

__global__ void f2b_mat_k(const float* __restrict__ in, unsigned short* __restrict__ out,
                          size_t n4) {
    size_t i = (size_t)blockIdx.x * blockDim.x + threadIdx.x;
    if (i >= n4) return;
    float4 v = ((const float4*)in)[i];
    ushort4 o;
    o.x = f2b(v.x); o.y = f2b(v.y); o.z = f2b(v.z); o.w = f2b(v.w);
    ((ushort4*)out)[i] = o;
}

// ---------------------------------------------------------------- mean aggregation
// bf16 in [n,C] -> bf16 out [n,C]. One wave per node. Wave split into NG edge-
// groups of GL lanes; each group gathers one edge row at 16 B/lane; 2x unroll
// -> up to 2*NG independent gathers in flight. Cross-group shfl_xor reduce.
template <int C>
__global__ void agg_k(const unsigned short* __restrict__ X, const int* __restrict__ row_ofs,
                      const int* __restrict__ csr, unsigned short* __restrict__ out, int n) {
    constexpr int GL = C / 8;      // lanes per group (8 bf16 = 16 B per lane)
    constexpr int NG = 64 / GL;    // groups per wave (C=128 -> 4, C=256 -> 2)
    int w = (int)((blockIdx.x * blockDim.x + threadIdx.x) >> 6);
    int lane = threadIdx.x & 63;
    if (w >= n) return;
    int g = lane / GL, il = lane % GL;
    int s = row_ofs[w], e = row_ofs[w + 1];
    float a[8] = {0.f, 0.f, 0.f, 0.f, 0.f, 0.f, 0.f, 0.f};

    int j = s + g;
    for (; j + NG < e; j += 2 * NG) {
        int i0 = csr[j], i1 = csr[j + NG];
        uint4 r0 = *(const uint4*)&X[(size_t)i0 * C + il * 8];
        uint4 r1 = *(const uint4*)&X[(size_t)i1 * C + il * 8];
        const unsigned short* p0 = (const unsigned short*)&r0;
        const unsigned short* p1 = (const unsigned short*)&r1;
        #pragma unroll
        for (int t = 0; t < 8; ++t) a[t] += b2f(p0[t]);
        #pragma unroll
        for (int t = 0; t < 8; ++t) a[t] += b2f(p1[t]);
    }
    if (j < e) {
        int i0 = csr[j];
        uint4 r0 = *(const uint4*)&X[(size_t)i0 * C + il * 8];
        const unsigned short* p0 = (const unsigned short*)&r0;
        #pragma unroll
        for (int t = 0; t < 8; ++t) a[t] += b2f(p0[t]);
    }

    // reduce across edge-groups (lanes with same il)
    #pragma unroll
    for (int m = GL; m < 64; m <<= 1)
        #pragma unroll
        for (int t = 0; t < 8; ++t) a[t] += __shfl_xor(a[t], m, 64);

    if (g == 0) {
        float inv = 1.0f / (float)max(e - s, 1);
        uint4 o;
        unsigned short* po = (unsigned short*)&o;
        #pragma unroll
        for (int t = 0; t < 8; ++t) po[t] = f2b(a[t] * inv);
        *(uint4*)&out[(size_t)w * C + il * 8] = o;
    }
}

// pool: bf16 input [N,256] -> fp32 pooled [G,256]; one wave per graph
__global__ void pool_mean_k(const unsigned short* __restrict__ H, const int* __restrict__ gofs,
                            float* __restrict__ pooled, int G) {
    int g = (int)((blockIdx.x * blockDim.x + threadIdx.x) >> 6);
    int lane = threadIdx.x & 63;
    if (g >= G) return;
    int s = gofs[g], e = gofs[g + 1];
    float a0 = 0.f, a1 = 0.f, a2 = 0.f, a3 = 0.f;
    for (int r = s; r < e; ++r) {
        ushort4 t = ((const ushort4*)(H + (size_t)r * HID))[lane];
        a0 += b2f(t.x); a1 += b2f(t.y); a2 += b2f(t.z); a3 += b2f(t.w);
    }
    float inv = 1.0f / (float)max(e - s, 1);
    float4 o; o.x = a0 * inv; o.y = a1 * inv; o.z = a2 * inv; o.w = a3 * inv;
    ((float4*)(pooled + (size_t)g * HID))[lane] = o;
}

// ---------------------------------------------------------------- bf16 MFMA GEMM
// C[M,Nfull] = act( [A1|A2][M,K1+K2] @ Bt[Nfull,K1+K2]^T + bias )
// 128x128 tile, 256 threads = 4 waves in 2x2, each wave 64x64 (4x4 MFMA frags), BK=32.
__launch_bounds__(256)
__global__ void mfma_gemm_k(const unsigned short* __restrict__ A1, int K1,
                            const unsigned short* __restrict__ A2, int K2,
                            const unsigned short* __restrict__ Bt,
                            const float* __restrict__ bias, int M, int Nfull,
                            void* __restrict__ Cptr, int c_bf16, int do_relu) {
    __shared__ short ldsA[128 * 32];
    __shared__ short ldsB[128 * 32];
    int tid = threadIdx.x, lane = tid & 63;
    int wid = tid >> 6, wm = wid >> 1, wn = wid & 1;
    int row0 = blockIdx.x * 128, col0 = blockIdx.y * 128;
    int q = lane >> 4, l15 = lane & 15;
    int KT = K1 + K2;

    f32x4 acc[4][4] = {};

    for (int kt = 0; kt < KT; kt += 32) {
        const unsigned short* Asrc; int kk, Ks;
        if (kt < K1) { Asrc = A1; kk = kt; Ks = K1; }
        else         { Asrc = A2; kk = kt - K1; Ks = K2; }
        #pragma unroll
        for (int h = 0; h < 2; ++h) {          // A tile [128 rows][32 k] bf16
            int c = tid + h * 256;             // 0..511 chunk of 8 bf16
            int r = c >> 2, c8 = (c & 3) * 8;
            int gr = min(row0 + r, M - 1);
            *(uint4*)&ldsA[r * 32 + c8] = *(const uint4*)&Asrc[(size_t)gr * Ks + kk + c8];
        }
        #pragma unroll
        for (int h = 0; h < 2; ++h) {          // B tile [128 n][32 k] bf16 (Bt rows)
            int c = tid + h * 256;
            int r = c >> 2, c8 = (c & 3) * 8;
            *(uint4*)&ldsB[r * 32 + c8] = *(const uint4*)&Bt[(size_t)(col0 + r) * KT + kt + c8];
        }
        __syncthreads();

        bf16x8 af[4], bfr[4];
        #pragma unroll
        for (int i = 0; i < 4; ++i)
            af[i] = *(const bf16x8*)&ldsA[(wm * 64 + i * 16 + l15) * 32 + q * 8];
        #pragma unroll
        for (int j = 0; j < 4; ++j)
            bfr[j] = *(const bf16x8*)&ldsB[(wn * 64 + j * 16 + l15) * 32 + q * 8];
        #pragma unroll
        for (int i = 0; i < 4; ++i)
            #pragma unroll
            for (int j = 0; j < 4; ++j)
                acc[i][j] = __builtin_amdgcn_mfma_f32_16x16x32_bf16(af[i], bfr[j], acc[i][j], 0, 0, 0);
        __syncthreads();
    }

    // epilogue: D layout col=lane&15, row=quad*4+reg
    #pragma unroll
    for (int i = 0; i < 4; ++i) {
        #pragma unroll
        for (int reg = 0; reg < 4; ++reg) {
            int r = row0 + wm * 64 + i * 16 + q * 4 + reg;
            if (r < M) {
                #pragma unroll
                for (int j = 0; j < 4; ++j) {
                    int cc = col0 + wn * 64 + j * 16 + l15;
                    float v = acc[i][j][reg] + bias[cc];
                    if (do_relu) v = fmaxf(v, 0.f);
                    if (c_bf16) ((unsigned short*)Cptr)[(size_t)r * Nfull + cc] = f2b(v);
                    else        ((float*)Cptr)[(size_t)r * Nfull + cc] = v;
                }
            }
        }
    }
}

// ---------------------------------------------------------------- fp32 GEMM (head only)
#define BM_ 64
#define BK_ 16

template <int BN_>
__launch_bounds__(256)
__global__ void gemm2_k(const float* __restrict__ A1, const float* __restrict__ B1, int K1,
                        const float* __restrict__ bias, float* __restrict__ C,
                        int M, int N, int do_relu) {
    constexpr int TCOLS = BN_ / 8;
    constexpr int TROWS = 256 / TCOLS;
    constexpr int TM = BM_ / TROWS;
    __shared__ float As[BK_][BM_ + 4];
    __shared__ float Bs[BK_][BN_ + 4];
    int tid = threadIdx.x;
    int row0 = blockIdx.x * BM_;
    int col0 = blockIdx.y * BN_;
    int tx = tid % TCOLS, ty = tid / TCOLS;

    float acc[TM][8];
    #pragma unroll
    for (int i = 0; i < TM; ++i)
        #pragma unroll
        for (int j = 0; j < 8; ++j) acc[i][j] = 0.f;

    int ar = tid >> 2;
    int ak = (tid & 3) * 4;

    for (int kt = 0; kt < K1; kt += BK_) {
        {
            int r = row0 + ar;
            int rc = min(r, M - 1);
            float4 v = *(const float4*)(A1 + (size_t)rc * K1 + kt + ak);
            As[ak + 0][ar] = v.x;
            As[ak + 1][ar] = v.y;
            As[ak + 2][ar] = v.z;
            As[ak + 3][ar] = v.w;
        }
        {
            #pragma unroll
            for (int h = 0; h < BN_ / 64; ++h) {
                int idx = h * 256 + tid;
                int kr = idx / (BN_ / 4);
                int c4 = idx % (BN_ / 4);
                float4 v = *(const float4*)(B1 + (size_t)(kt + kr) * N + col0 + c4 * 4);
                *(float4*)&Bs[kr][c4 * 4] = v;
            }
        }
        __syncthreads();

        #pragma unroll
        for (int k = 0; k < BK_; ++k) {
            float a[TM], b[8];
            #pragma unroll
            for (int v = 0; v < TM / 4; ++v)
                *(float4*)&a[v * 4] = *(const float4*)&As[k][ty * TM + v * 4];
            *(float4*)&b[0] = *(const float4*)&Bs[k][tx * 8];
            *(float4*)&b[4] = *(const float4*)&Bs[k][tx * 8 + 4];
            #pragma unroll
            for (int i = 0; i < TM; ++i)
                #pragma unroll
                for (int j = 0; j < 8; ++j) acc[i][j] = fmaf(a[i], b[j], acc[i][j]);
        }
        __syncthreads();
    }

    float bv[8];
    #pragma unroll
    for (int j = 0; j < 8; ++j) bv[j] = bias[col0 + tx * 8 + j];
    #pragma unroll
    for (int i = 0; i < TM; ++i) {
        int r = row0 + ty * TM + i;
        if (r < M) {
            float* cp = C + (size_t)r * N + col0 + tx * 8;
            float o[8];
            #pragma unroll
            for (int j = 0; j < 8; ++j) {
                float v = acc[i][j] + bv[j];
                o[j] = do_relu ? fmaxf(v, 0.f) : v;
            }
            *(float4*)(cp + 0) = *(float4*)&o[0];
            *(float4*)(cp + 4) = *(float4*)&o[4];
        }
    }
}

// ---------------------------------------------------------------- launcher
extern "C" void kernel_launch(void* const* d_in, const int* in_sizes, int n_in,
                              void* d_out, int out_size, void* d_ws, size_t ws_size,
                              hipStream_t stream) {
    const float* x    = (const float*)d_in[0];
    const int*   ei   = (const int*)d_in[1];
    const int*   batch= (const int*)d_in[2];
    const float* W1l  = (const float*)d_in[3];
    const float* b1   = (const float*)d_in[4];
    const float* W1r  = (const float*)d_in[5];
    const float* W2l  = (const float*)d_in[6];
    const float* b2   = (const float*)d_in[7];
    const float* W2r  = (const float*)d_in[8];
    const float* W3   = (const float*)d_in[9];
    const float* b3   = (const float*)d_in[10];
    const float* W4   = (const float*)d_in[11];
    const float* b4   = (const float*)d_in[12];
    float* out = (float*)d_out;

    const int N = N_NODES, E = N_EDGES, G = N_GRAPHS;
    const int* src = ei;
    const int* dst = ei + E;

    char* ws = (char*)d_ws;
    size_t off = 0;
    auto alloc = [&](size_t bytes) -> char* {
        off = (off + 255) & ~(size_t)255;
        char* p = ws + off;
        off += bytes;
        return p;
    };
    int* deg     = (int*)alloc((size_t)N * 4);
    int* cursor  = (int*)alloc((size_t)N * 4);
    size_t zero_span = (size_t)((char*)(cursor + N) - (char*)deg);
    int* row_ofs = (int*)alloc((size_t)(N + 1) * 4);
    int* gofs    = (int*)alloc((size_t)(G + 1) * 4);
    int* bsums   = (int*)alloc(256 * 4);
    int* csr     = (int*)alloc((size_t)E * 4);
    unsigned short* xb    = (unsigned short*)alloc((size_t)N * IN_CH * 2);
    unsigned short* mean1 = (unsigned short*)alloc((size_t)N * IN_CH * 2);
    unsigned short* h1    = (unsigned short*)alloc((size_t)N * HID * 2);
    unsigned short* mean2 = (unsigned short*)alloc((size_t)N * HID * 2);
    unsigned short* h2    = xb;  // xb+mean1 contiguous span reused for h2 [N,256]
    unsigned short* W1T   = (unsigned short*)alloc((size_t)HID * (IN_CH + IN_CH) * 2);
    unsigned short* W2T   = (unsigned short*)alloc((size_t)HID * (HID + HID) * 2);
    float* pooled = (float*)alloc((size_t)G * HID * 4);
    float* hidden = (float*)alloc((size_t)G * HID * 4);
    (void)ws_size;

    hipMemsetAsync(deg, 0, zero_span, stream);

    count_edges_k<<<(E + 255) / 256, 256, 0, stream>>>(dst, deg, E);

    const int nb = (N + SCAN_TILE - 1) / SCAN_TILE;
    scan1_k<<<nb, 256, 0, stream>>>(deg, row_ofs, bsums, N);
    scan2_k<<<1, 256, 0, stream>>>(bsums, nb, row_ofs + N);
    scan3_k<<<nb, 256, 0, stream>>>(row_ofs, bsums, N);

    gofs_search_k<<<(G + 256) / 256, 256, 0, stream>>>(batch, gofs, N, G);

    fill_csr_k<<<(E + 255) / 256, 256, 0, stream>>>(src, dst, row_ofs, cursor, csr, E);

    wt_concat_k<<<(HID * 2 * IN_CH + 255) / 256, 256, 0, stream>>>(W1l, W1r, W1T, IN_CH, IN_CH, HID);
    wt_concat_k<<<(HID * 2 * HID + 255) / 256, 256, 0, stream>>>(W2l, W2r, W2T, HID, HID, HID);
    f2b_mat_k<<<((N * IN_CH / 4) + 255) / 256, 256, 0, stream>>>(x, xb, (size_t)N * IN_CH / 4);

    const int MB = (N + 127) / 128;

    // layer 1: mean1 = bf16 mean-agg(xb); h1 = relu([mean1|xb] @ W1T^T + b1)
    agg_k<IN_CH><<<(N + 3) / 4, 256, 0, stream>>>(xb, row_ofs, csr, mean1, N);
    mfma_gemm_k<<<dim3(MB, HID / 128), 256, 0, stream>>>(
        mean1, IN_CH, xb, IN_CH, W1T, b1, N, HID, h1, 1, 1);

    // layer 2: mean2 = bf16 mean-agg(h1); h2 = relu([mean2|h1] @ W2T^T + b2)
    agg_k<HID><<<(N + 3) / 4, 256, 0, stream>>>(h1, row_ofs, csr, mean2, N);
    mfma_gemm_k<<<dim3(MB, HID / 128), 256, 0, stream>>>(
        mean2, HID, h1, HID, W2T, b2, N, HID, h2, 1, 1);

    // global mean pool (bf16 in, fp32 out)
    pool_mean_k<<<(G + 3) / 4, 256, 0, stream>>>(h2, gofs, pooled, G);

    // MLP head (fp32)
    gemm2_k<HID><<<dim3(G / BM_, 1), 256, 0, stream>>>(
        pooled, W3, HID, b3, hidden, G, HID, 1);
    gemm2_k<OUT_CH><<<dim3(G / BM_, 1), 256, 0, stream>>>(
        hidden, W4, HID, b4, out, G, OUT_CH, 0);
}

// Round 6
// 641.115 us; speedup vs baseline: 2.6120x; 1.0493x over previous
//
#include <hip/hip_runtime.h>

#define N_NODES 100000
#define N_EDGES 1600000
#define IN_CH 128
#define HID 256
#define OUT_CH 128
#define N_GRAPHS 2048

typedef __attribute__((ext_vector_type(8))) short bf16x8;
typedef __attribute__((ext_vector_type(4))) float f32x4;
typedef __attribute__((ext_vector_type(2))) float f32x2;

__device__ inline unsigned short f2b(float f) {  // RNE fp32 -> bf16
    unsigned int u = __builtin_bit_cast(unsigned int, f);
    u = (u + 0x7FFF + ((u >> 16) & 1)) >> 16;
    return (unsigned short)u;
}
__device__ inline float b2f(unsigned short h) {
    unsigned int u = (unsigned int)h << 16;
    return __builtin_bit_cast(float, u);
}

// ---------------------------------------------------------------- CSR build
__global__ void count_edges_k(const int* __restrict__ dst, int* __restrict__ deg, int E) {
    int e = blockIdx.x * blockDim.x + threadIdx.x;
    if (e < E) atomicAdd(&deg[dst[e]], 1);
}

#define SCAN_ITEMS 8
#define SCAN_TILE (256 * SCAN_ITEMS)

__global__ void scan1_k(const int* __restrict__ in, int* __restrict__ out,
                        int* __restrict__ bsums, int n) {
    __shared__ int wsum[4];
    int base = blockIdx.x * SCAN_TILE + (int)threadIdx.x * SCAN_ITEMS;
    int v[SCAN_ITEMS];
    int s = 0;
    #pragma unroll
    for (int i = 0; i < SCAN_ITEMS; ++i) {
        v[i] = (base + i < n) ? in[base + i] : 0;
        s += v[i];
    }
    int lane = threadIdx.x & 63, wid = threadIdx.x >> 6;
    int incl = s;
    #pragma unroll
    for (int off = 1; off < 64; off <<= 1) {
        int t = __shfl_up(incl, off, 64);
        if (lane >= off) incl += t;
    }
    if (lane == 63) wsum[wid] = incl;
    __syncthreads();
    int wprefix = 0;
    #pragma unroll
    for (int w = 0; w < 4; ++w)
        if (w < wid) wprefix += wsum[w];
    int run = wprefix + incl - s;
    #pragma unroll
    for (int i = 0; i < SCAN_ITEMS; ++i) {
        if (base + i < n) out[base + i] = run;
        run += v[i];
    }
    if (threadIdx.x == 255) bsums[blockIdx.x] = wprefix + incl;
}

__global__ void scan2_k(int* __restrict__ bsums, int nb, int* __restrict__ total) {
    __shared__ int wsum[4];
    int v = ((int)threadIdx.x < nb) ? bsums[threadIdx.x] : 0;
    int lane = threadIdx.x & 63, wid = threadIdx.x >> 6;
    int incl = v;
    #pragma unroll
    for (int off = 1; off < 64; off <<= 1) {
        int t = __shfl_up(incl, off, 64);
        if (lane >= off) incl += t;
    }
    if (lane == 63) wsum[wid] = incl;
    __syncthreads();
    int wprefix = 0;
    #pragma unroll
    for (int w = 0; w < 4; ++w)
        if (w < wid) wprefix += wsum[w];
    if ((int)threadIdx.x < nb) bsums[threadIdx.x] = wprefix + incl - v;
    if (threadIdx.x == 255) *total = wprefix + incl;
}

__global__ void scan3_k(int* __restrict__ out, const int* __restrict__ bsums, int n) {
    int add = bsums[blockIdx.x];
    int base = blockIdx.x * SCAN_TILE + (int)threadIdx.x * SCAN_ITEMS;
    #pragma unroll
    for (int i = 0; i < SCAN_ITEMS; ++i)
        if (base + i < n) out[base + i] += add;
}

__global__ void gofs_search_k(const int* __restrict__ batch, int* __restrict__ gofs,
                              int n, int G) {
    int g = blockIdx.x * blockDim.x + threadIdx.x;
    if (g > G) return;
    if (g == G) { gofs[G] = n; return; }
    int lo = 0, hi = n;
    while (lo < hi) {
        int mid = (lo + hi) >> 1;
        if (batch[mid] < g) lo = mid + 1; else hi = mid;
    }
    gofs[g] = lo;
}

__global__ void fill_csr_k(const int* __restrict__ src, const int* __restrict__ dst,
                           const int* __restrict__ row_ofs, int* __restrict__ cursor,
                           int* __restrict__ csr, int E) {
    int e = blockIdx.x * blockDim.x + threadIdx.x;
    if (e >= E) return;
    int d = dst[e];
    int pos = atomicAdd(&cursor[d], 1);
    csr[row_ofs[d] + pos] = src[e];
}

// ---------------------------------------------------------------- converts
__global__ void wt_concat_k(const float* __restrict__ Wl, const float* __restrict__ Wr,
                            unsigned short* __restrict__ out, int K1, int K2, int N) {
    int idx = blockIdx.x * blockDim.x + threadIdx.x;
    int KT = K1 + K2;
    if (idx >= N * KT) return;
    int n = idx / KT, k = idx % KT;
    float v = (k < K1) ? Wl[(size_t)k * N + n] : Wr[(size_t)(k - K1) * N + n];
    out[idx] = f2b(v);
}

__global__ void f2b_mat_k(const float* __restrict__ in, unsigned short* __restrict__ out,
                          size_t n4) {
    size_t i = (size_t)blockIdx.x * blockDim.x + threadIdx.x;
    if (i >= n4) return;
    float4 v = ((const float4*)in)[i];
    ushort4 o;
    o.x = f2b(v.x); o.y = f2b(v.y); o.z = f2b(v.z); o.w = f2b(v.w);
    ((ushort4*)out)[i] = o;
}

// bf16 -> fp8 e4m3 (HW cvt). Each thread: 16 bf16 in (32B) -> 16 fp8 out (16B).
__global__ void b2f8_k(const unsigned short* __restrict__ in, unsigned char* __restrict__ out,
                       size_t n16) {
    size_t i = (size_t)blockIdx.x * blockDim.x + threadIdx.x;
    if (i >= n16) return;
    uint4 v0 = ((const uint4*)in)[i * 2];
    uint4 v1 = ((const uint4*)in)[i * 2 + 1];
    const unsigned int* q = (const unsigned int*)&v0;
    const unsigned int* r = (const unsigned int*)&v1;
    uint4 o;
    unsigned int* po = (unsigned int*)&o;
    #pragma unroll
    for (int t = 0; t < 2; ++t) {
        int w = 0;
        w = __builtin_amdgcn_cvt_pk_fp8_f32(b2f((unsigned short)(q[t * 2] & 0xFFFF)),
                                            b2f((unsigned short)(q[t * 2] >> 16)), w, false);
        w = __builtin_amdgcn_cvt_pk_fp8_f32(b2f((unsigned short)(q[t * 2 + 1] & 0xFFFF)),
                                            b2f((unsigned short)(q[t * 2 + 1] >> 16)), w, true);
        po[t] = (unsigned int)w;
    }
    #pragma unroll
    for (int t = 0; t < 2; ++t) {
        int w = 0;
        w = __builtin_amdgcn_cvt_pk_fp8_f32(b2f((unsigned short)(r[t * 2] & 0xFFFF)),
                                            b2f((unsigned short)(r[t * 2] >> 16)), w, false);
        w = __builtin_amdgcn_cvt_pk_fp8_f32(b2f((unsigned short)(r[t * 2 + 1] & 0xFFFF)),
                                            b2f((unsigned short)(r[t * 2 + 1] >> 16)), w, true);
        po[2 + t] = (unsigned int)w;
    }
    ((uint4*)out)[i] = o;
}

// ---------------------------------------------------------------- mean aggregation
// bf16 in [n,C] -> bf16 out [n,C]. One wave per node, NG edge-groups x GL lanes,
// 16 B/lane per gather, 2x unroll. Cross-group shfl_xor reduce.
template <int C>
__global__ void agg_k(const unsigned short* __restrict__ X, const int* __restrict__ row_ofs,
                      const int* __restrict__ csr, unsigned short* __restrict__ out, int n) {
    constexpr int GL = C / 8;      // lanes per group (8 bf16 = 16 B per lane)
    constexpr int NG = 64 / GL;    // groups per wave
    int w = (int)((blockIdx.x * blockDim.x + threadIdx.x) >> 6);
    int lane = threadIdx.x & 63;
    if (w >= n) return;
    int g = lane / GL, il = lane % GL;
    int s = row_ofs[w], e = row_ofs[w + 1];
    float a[8] = {0.f, 0.f, 0.f, 0.f, 0.f, 0.f, 0.f, 0.f};

    int j = s + g;
    for (; j + NG < e; j += 2 * NG) {
        int i0 = csr[j], i1 = csr[j + NG];
        uint4 r0 = *(const uint4*)&X[(size_t)i0 * C + il * 8];
        uint4 r1 = *(const uint4*)&X[(size_t)i1 * C + il * 8];
        const unsigned short* p0 = (const unsigned short*)&r0;
        const unsigned short* p1 = (const unsigned short*)&r1;
        #pragma unroll
        for (int t = 0; t < 8; ++t) a[t] += b2f(p0[t]);
        #pragma unroll
        for (int t = 0; t < 8; ++t) a[t] += b2f(p1[t]);
    }
    if (j < e) {
        int i0 = csr[j];
        uint4 r0 = *(const uint4*)&X[(size_t)i0 * C + il * 8];
        const unsigned short* p0 = (const unsigned short*)&r0;
        #pragma unroll
        for (int t = 0; t < 8; ++t) a[t] += b2f(p0[t]);
    }

    #pragma unroll
    for (int m = GL; m < 64; m <<= 1)
        #pragma unroll
        for (int t = 0; t < 8; ++t) a[t] += __shfl_xor(a[t], m, 64);

    if (g == 0) {
        float inv = 1.0f / (float)max(e - s, 1);
        uint4 o;
        unsigned short* po = (unsigned short*)&o;
        #pragma unroll
        for (int t = 0; t < 8; ++t) po[t] = f2b(a[t] * inv);
        *(uint4*)&out[(size_t)w * C + il * 8] = o;
    }
}

// fp8 in [n,256] -> bf16 mean out [n,256]. Row = 256B; 16 lanes x 16B, NG=4, 2x unroll.
__global__ void agg2_f8_k(const unsigned char* __restrict__ X8, const int* __restrict__ row_ofs,
                          const int* __restrict__ csr, unsigned short* __restrict__ out, int n) {
    int w = (int)((blockIdx.x * blockDim.x + threadIdx.x) >> 6);
    int lane = threadIdx.x & 63;
    if (w >= n) return;
    int g = lane >> 4, il = lane & 15;   // 4 groups of 16 lanes
    int s = row_ofs[w], e = row_ofs[w + 1];
    float a[16];
    #pragma unroll
    for (int t = 0; t < 16; ++t) a[t] = 0.f;

    int j = s + g;
    for (; j + 4 < e; j += 8) {
        int i0 = csr[j], i1 = csr[j + 4];
        uint4 r0 = *(const uint4*)&X8[(size_t)i0 * HID + il * 16];
        uint4 r1 = *(const uint4*)&X8[(size_t)i1 * HID + il * 16];
        const unsigned int* q0 = (const unsigned int*)&r0;
        const unsigned int* q1 = (const unsigned int*)&r1;
        #pragma unroll
        for (int t = 0; t < 4; ++t) {
            f32x2 lo = __builtin_amdgcn_cvt_pk_f32_fp8(q0[t], false);
            f32x2 hi = __builtin_amdgcn_cvt_pk_f32_fp8(q0[t], true);
            a[t * 4 + 0] += lo.x; a[t * 4 + 1] += lo.y;
            a[t * 4 + 2] += hi.x; a[t * 4 + 3] += hi.y;
        }
        #pragma unroll
        for (int t = 0; t < 4; ++t) {
            f32x2 lo = __builtin_amdgcn_cvt_pk_f32_fp8(q1[t], false);
            f32x2 hi = __builtin_amdgcn_cvt_pk_f32_fp8(q1[t], true);
            a[t * 4 + 0] += lo.x; a[t * 4 + 1] += lo.y;
            a[t * 4 + 2] += hi.x; a[t * 4 + 3] += hi.y;
        }
    }
    if (j < e) {
        int i0 = csr[j];
        uint4 r0 = *(const uint4*)&X8[(size_t)i0 * HID + il * 16];
        const unsigned int* q0 = (const unsigned int*)&r0;
        #pragma unroll
        for (int t = 0; t < 4; ++t) {
            f32x2 lo = __builtin_amdgcn_cvt_pk_f32_fp8(q0[t], false);
            f32x2 hi = __builtin_amdgcn_cvt_pk_f32_fp8(q0[t], true);
            a[t * 4 + 0] += lo.x; a[t * 4 + 1] += lo.y;
            a[t * 4 + 2] += hi.x; a[t * 4 + 3] += hi.y;
        }
    }

    #pragma unroll
    for (int m = 16; m < 64; m <<= 1)
        #pragma unroll
        for (int t = 0; t < 16; ++t) a[t] += __shfl_xor(a[t], m, 64);

    if (g == 0) {
        float inv = 1.0f / (float)max(e - s, 1);
        uint4 o0, o1;
        unsigned short* p0 = (unsigned short*)&o0;
        unsigned short* p1 = (unsigned short*)&o1;
        #pragma unroll
        for (int t = 0; t < 8; ++t) p0[t] = f2b(a[t] * inv);
        #pragma unroll
        for (int t = 0; t < 8; ++t) p1[t] = f2b(a[8 + t] * inv);
        *(uint4*)&out[(size_t)w * HID + il * 16] = o0;
        *(uint4*)&out[(size_t)w * HID + il * 16 + 8] = o1;
    }
}

// pool: bf16 input [N,256] -> fp32 pooled [G,256]; one wave per graph
__global__ void pool_mean_k(const unsigned short* __restrict__ H, const int* __restrict__ gofs,
                            float* __restrict__ pooled, int G) {
    int g = (int)((blockIdx.x * blockDim.x + threadIdx.x) >> 6);
    int lane = threadIdx.x & 63;
    if (g >= G) return;
    int s = gofs[g], e = gofs[g + 1];
    float a0 = 0.f, a1 = 0.f, a2 = 0.f, a3 = 0.f;
    for (int r = s; r < e; ++r) {
        ushort4 t = ((const ushort4*)(H + (size_t)r * HID))[lane];
        a0 += b2f(t.x); a1 += b2f(t.y); a2 += b2f(t.z); a3 += b2f(t.w);
    }
    float inv = 1.0f / (float)max(e - s, 1);
    float4 o; o.x = a0 * inv; o.y = a1 * inv; o.z = a2 * inv; o.w = a3 * inv;
    ((float4*)(pooled + (size_t)g * HID))[lane] = o;
}

// ---------------------------------------------------------------- bf16 MFMA GEMM
__launch_bounds__(256)
__global__ void mfma_gemm_k(const unsigned short* __restrict__ A1, int K1,
                            const unsigned short* __restrict__ A2, int K2,
                            const unsigned short* __restrict__ Bt,
                            const float* __restrict__ bias, int M, int Nfull,
                            void* __restrict__ Cptr, int c_bf16, int do_relu) {
    __shared__ short ldsA[128 * 32];
    __shared__ short ldsB[128 * 32];
    int tid = threadIdx.x, lane = tid & 63;
    int wid = tid >> 6, wm = wid >> 1, wn = wid & 1;
    int row0 = blockIdx.x * 128, col0 = blockIdx.y * 128;
    int q = lane >> 4, l15 = lane & 15;
    int KT = K1 + K2;

    f32x4 acc[4][4] = {};

    for (int kt = 0; kt < KT; kt += 32) {
        const unsigned short* Asrc; int kk, Ks;
        if (kt < K1) { Asrc = A1; kk = kt; Ks = K1; }
        else         { Asrc = A2; kk = kt - K1; Ks = K2; }
        #pragma unroll
        for (int h = 0; h < 2; ++h) {
            int c = tid + h * 256;
            int r = c >> 2, c8 = (c & 3) * 8;
            int gr = min(row0 + r, M - 1);
            *(uint4*)&ldsA[r * 32 + c8] = *(const uint4*)&Asrc[(size_t)gr * Ks + kk + c8];
        }
        #pragma unroll
        for (int h = 0; h < 2; ++h) {
            int c = tid + h * 256;
            int r = c >> 2, c8 = (c & 3) * 8;
            *(uint4*)&ldsB[r * 32 + c8] = *(const uint4*)&Bt[(size_t)(col0 + r) * KT + kt + c8];
        }
        __syncthreads();

        bf16x8 af[4], bfr[4];
        #pragma unroll
        for (int i = 0; i < 4; ++i)
            af[i] = *(const bf16x8*)&ldsA[(wm * 64 + i * 16 + l15) * 32 + q * 8];
        #pragma unroll
        for (int j = 0; j < 4; ++j)
            bfr[j] = *(const bf16x8*)&ldsB[(wn * 64 + j * 16 + l15) * 32 + q * 8];
        #pragma unroll
        for (int i = 0; i < 4; ++i)
            #pragma unroll
            for (int j = 0; j < 4; ++j)
                acc[i][j] = __builtin_amdgcn_mfma_f32_16x16x32_bf16(af[i], bfr[j], acc[i][j], 0, 0, 0);
        __syncthreads();
    }

    #pragma unroll
    for (int i = 0; i < 4; ++i) {
        #pragma unroll
        for (int reg = 0; reg < 4; ++reg) {
            int r = row0 + wm * 64 + i * 16 + q * 4 + reg;
            if (r < M) {
                #pragma unroll
                for (int j = 0; j < 4; ++j) {
                    int cc = col0 + wn * 64 + j * 16 + l15;
                    float v = acc[i][j][reg] + bias[cc];
                    if (do_relu) v = fmaxf(v, 0.f);
                    if (c_bf16) ((unsigned short*)Cptr)[(size_t)r * Nfull + cc] = f2b(v);
                    else        ((float*)Cptr)[(size_t)r * Nfull + cc] = v;
                }
            }
        }
    }
}

// ---------------------------------------------------------------- fp32 GEMM (head only)
#define BM_ 64
#define BK_ 16

template <int BN_>
__launch_bounds__(256)
__global__ void gemm2_k(const float* __restrict__ A1, const float* __restrict__ B1, int K1,
                        const float* __restrict__ bias, float* __restrict__ C,
                        int M, int N, int do_relu) {
    constexpr int TCOLS = BN_ / 8;
    constexpr int TROWS = 256 / TCOLS;
    constexpr int TM = BM_ / TROWS;
    __shared__ float As[BK_][BM_ + 4];
    __shared__ float Bs[BK_][BN_ + 4];
    int tid = threadIdx.x;
    int row0 = blockIdx.x * BM_;
    int col0 = blockIdx.y * BN_;
    int tx = tid % TCOLS, ty = tid / TCOLS;

    float acc[TM][8];
    #pragma unroll
    for (int i = 0; i < TM; ++i)
        #pragma unroll
        for (int j = 0; j < 8; ++j) acc[i][j] = 0.f;

    int ar = tid >> 2;
    int ak = (tid & 3) * 4;

    for (int kt = 0; kt < K1; kt += BK_) {
        {
            int r = row0 + ar;
            int rc = min(r, M - 1);
            float4 v = *(const float4*)(A1 + (size_t)rc * K1 + kt + ak);
            As[ak + 0][ar] = v.x;
            As[ak + 1][ar] = v.y;
            As[ak + 2][ar] = v.z;
            As[ak + 3][ar] = v.w;
        }
        {
            #pragma unroll
            for (int h = 0; h < BN_ / 64; ++h) {
                int idx = h * 256 + tid;
                int kr = idx / (BN_ / 4);
                int c4 = idx % (BN_ / 4);
                float4 v = *(const float4*)(B1 + (size_t)(kt + kr) * N + col0 + c4 * 4);
                *(float4*)&Bs[kr][c4 * 4] = v;
            }
        }
        __syncthreads();

        #pragma unroll
        for (int k = 0; k < BK_; ++k) {
            float a[TM], b[8];
            #pragma unroll
            for (int v = 0; v < TM / 4; ++v)
                *(float4*)&a[v * 4] = *(const float4*)&As[k][ty * TM + v * 4];
            *(float4*)&b[0] = *(const float4*)&Bs[k][tx * 8];
            *(float4*)&b[4] = *(const float4*)&Bs[k][tx * 8 + 4];
            #pragma unroll
            for (int i = 0; i < TM; ++i)
                #pragma unroll
                for (int j = 0; j < 8; ++j) acc[i][j] = fmaf(a[i], b[j], acc[i][j]);
        }
        __syncthreads();
    }

    float bv[8];
    #pragma unroll
    for (int j = 0; j < 8; ++j) bv[j] = bias[col0 + tx * 8 + j];
    #pragma unroll
    for (int i = 0; i < TM; ++i) {
        int r = row0 + ty * TM + i;
        if (r < M) {
            float* cp = C + (size_t)r * N + col0 + tx * 8;
            float o[8];
            #pragma unroll
            for (int j = 0; j < 8; ++j) {
                float v = acc[i][j] + bv[j];
                o[j] = do_relu ? fmaxf(v, 0.f) : v;
            }
            *(float4*)(cp + 0) = *(float4*)&o[0];
            *(float4*)(cp + 4) = *(float4*)&o[4];
        }
    }
}

// ---------------------------------------------------------------- launcher
extern "C" void kernel_launch(void* const* d_in, const int* in_sizes, int n_in,
                              void* d_out, int out_size, void* d_ws, size_t ws_size,
                              hipStream_t stream) {
    const float* x    = (const float*)d_in[0];
    const int*   ei   = (const int*)d_in[1];
    const int*   batch= (const int*)d_in[2];
    const float* W1l  = (const float*)d_in[3];
    const float* b1   = (const float*)d_in[4];
    const float* W1r  = (const float*)d_in[5];
    const float* W2l  = (const float*)d_in[6];
    const float* b2   = (const float*)d_in[7];
    const float* W2r  = (const float*)d_in[8];
    const float* W3   = (const float*)d_in[9];
    const float* b3   = (const float*)d_in[10];
    const float* W4   = (const float*)d_in[11];
    const float* b4   = (const float*)d_in[12];
    float* out = (float*)d_out;

    const int N = N_NODES, E = N_EDGES, G = N_GRAPHS;
    const int* src = ei;
    const int* dst = ei + E;

    char* ws = (char*)d_ws;
    size_t off = 0;
    auto alloc = [&](size_t bytes) -> char* {
        off = (off + 255) & ~(size_t)255;
        char* p = ws + off;
        off += bytes;
        return p;
    };
    int* deg     = (int*)alloc((size_t)N * 4);
    int* cursor  = (int*)alloc((size_t)N * 4);
    size_t zero_span = (size_t)((char*)(cursor + N) - (char*)deg);
    int* row_ofs = (int*)alloc((size_t)(N + 1) * 4);
    int* gofs    = (int*)alloc((size_t)(G + 1) * 4);
    int* bsums   = (int*)alloc(256 * 4);
    int* csr     = (int*)alloc((size_t)E * 4);
    unsigned short* xb    = (unsigned short*)alloc((size_t)N * IN_CH * 2);
    unsigned short* mean1 = (unsigned short*)alloc((size_t)N * IN_CH * 2);
    unsigned short* h1    = (unsigned short*)alloc((size_t)N * HID * 2);
    unsigned short* mean2 = (unsigned short*)alloc((size_t)N * HID * 2);
    unsigned short* h2    = xb;  // xb+mean1 contiguous span reused for h2 [N,256]
    unsigned char*  h1f8  = (unsigned char*)alloc((size_t)N * HID);
    unsigned short* W1T   = (unsigned short*)alloc((size_t)HID * (IN_CH + IN_CH) * 2);
    unsigned short* W2T   = (unsigned short*)alloc((size_t)HID * (HID + HID) * 2);
    float* pooled = (float*)alloc((size_t)G * HID * 4);
    float* hidden = (float*)alloc((size_t)G * HID * 4);
    (void)ws_size;

    hipMemsetAsync(deg, 0, zero_span, stream);

    count_edges_k<<<(E + 255) / 256, 256, 0, stream>>>(dst, deg, E);

    const int nb = (N + SCAN_TILE - 1) / SCAN_TILE;
    scan1_k<<<nb, 256, 0, stream>>>(deg, row_ofs, bsums, N);
    scan2_k<<<1, 256, 0, stream>>>(bsums, nb, row_ofs + N);
    scan3_k<<<nb, 256, 0, stream>>>(row_ofs, bsums, N);

    gofs_search_k<<<(G + 256) / 256, 256, 0, stream>>>(batch, gofs, N, G);

    fill_csr_k<<<(E + 255) / 256, 256, 0, stream>>>(src, dst, row_ofs, cursor, csr, E);

    wt_concat_k<<<(HID * 2 * IN_CH + 255) / 256, 256, 0, stream>>>(W1l, W1r, W1T, IN_CH, IN_CH, HID);
    wt_concat_k<<<(HID * 2 * HID + 255) / 256, 256, 0, stream>>>(W2l, W2r, W2T, HID, HID, HID);
    f2b_mat_k<<<((N * IN_CH / 4) + 255) / 256, 256, 0, stream>>>(x, xb, (size_t)N * IN_CH / 4);

    const int MB = (N + 127) / 128;

    // layer 1: mean1 = bf16 mean-agg(xb); h1 = relu([mean1|xb] @ W1T^T + b1)
    agg_k<IN_CH><<<(N + 3) / 4, 256, 0, stream>>>(xb, row_ofs, csr, mean1, N);
    mfma_gemm_k<<<dim3(MB, HID / 128), 256, 0, stream>>>(
        mean1, IN_CH, xb, IN_CH, W1T, b1, N, HID, h1, 1, 1);

    // fp8 mirror of h1 for the layer-2 gather
    b2f8_k<<<(int)(((size_t)N * HID / 16 + 255) / 256), 256, 0, stream>>>(
        h1, h1f8, (size_t)N * HID / 16);

    // layer 2: mean2 = mean-agg(h1f8) [fp8 gather]; h2 = relu([mean2|h1] @ W2T^T + b2)
    agg2_f8_k<<<(N + 3) / 4, 256, 0, stream>>>(h1f8, row_ofs, csr, mean2, N);
    mfma_gemm_k<<<dim3(MB, HID / 128), 256, 0, stream>>>(
        mean2, HID, h1, HID, W2T, b2, N, HID, h2, 1, 1);

    // global mean pool (bf16 in, fp32 out)
    pool_mean_k<<<(G + 3) / 4, 256, 0, stream>>>(h2, gofs, pooled, G);

    // MLP head (fp32)
    gemm2_k<HID><<<dim3(G / BM_, 1), 256, 0, stream>>>(
        pooled, W3, HID, b3, hidden, G, HID, 1);
    gemm2_k<OUT_CH><<<dim3(G / BM_, 1), 256, 0, stream>>>(
        hidden, W4, HID, b4, out, G, OUT_CH, 0);
}

// Round 7
// 634.232 us; speedup vs baseline: 2.6403x; 1.0109x over previous
//
#include <hip/hip_runtime.h>

#define N_NODES 100000
#define N_EDGES 1600000
#define IN_CH 128
#define HID 256
#define OUT_CH 128
#define N_GRAPHS 2048

typedef __attribute__((ext_vector_type(8))) short bf16x8;
typedef __attribute__((ext_vector_type(4))) float f32x4;
typedef __attribute__((ext_vector_type(2))) float f32x2;

__device__ inline unsigned short f2b(float f) {  // RNE fp32 -> bf16
    unsigned int u = __builtin_bit_cast(unsigned int, f);
    u = (u + 0x7FFF + ((u >> 16) & 1)) >> 16;
    return (unsigned short)u;
}
__device__ inline float b2f(unsigned short h) {
    unsigned int u = (unsigned int)h << 16;
    return __builtin_bit_cast(float, u);
}

// async global->LDS, 16 B per lane; dst is wave-uniform base, HW adds lane*16
#define GLOAD_LDS16(gsrc, ldst)                                                   \
    __builtin_amdgcn_global_load_lds(                                             \
        (const __attribute__((address_space(1))) void*)(gsrc),                    \
        (__attribute__((address_space(3))) void*)(ldst), 16, 0, 0)

// ---------------------------------------------------------------- CSR build
__global__ void count_edges_k(const int* __restrict__ dst, int* __restrict__ deg, int E) {
    int e = blockIdx.x * blockDim.x + threadIdx.x;
    if (e < E) atomicAdd(&deg[dst[e]], 1);
}

#define SCAN_ITEMS 8
#define SCAN_TILE (256 * SCAN_ITEMS)

__global__ void scan1_k(const int* __restrict__ in, int* __restrict__ out,
                        int* __restrict__ bsums, int n) {
    __shared__ int wsum[4];
    int base = blockIdx.x * SCAN_TILE + (int)threadIdx.x * SCAN_ITEMS;
    int v[SCAN_ITEMS];
    int s = 0;
    #pragma unroll
    for (int i = 0; i < SCAN_ITEMS; ++i) {
        v[i] = (base + i < n) ? in[base + i] : 0;
        s += v[i];
    }
    int lane = threadIdx.x & 63, wid = threadIdx.x >> 6;
    int incl = s;
    #pragma unroll
    for (int off = 1; off < 64; off <<= 1) {
        int t = __shfl_up(incl, off, 64);
        if (lane >= off) incl += t;
    }
    if (lane == 63) wsum[wid] = incl;
    __syncthreads();
    int wprefix = 0;
    #pragma unroll
    for (int w = 0; w < 4; ++w)
        if (w < wid) wprefix += wsum[w];
    int run = wprefix + incl - s;
    #pragma unroll
    for (int i = 0; i < SCAN_ITEMS; ++i) {
        if (base + i < n) out[base + i] = run;
        run += v[i];
    }
    if (threadIdx.x == 255) bsums[blockIdx.x] = wprefix + incl;
}

__global__ void scan2_k(int* __restrict__ bsums, int nb, int* __restrict__ total) {
    __shared__ int wsum[4];
    int v = ((int)threadIdx.x < nb) ? bsums[threadIdx.x] : 0;
    int lane = threadIdx.x & 63, wid = threadIdx.x >> 6;
    int incl = v;
    #pragma unroll
    for (int off = 1; off < 64; off <<= 1) {
        int t = __shfl_up(incl, off, 64);
        if (lane >= off) incl += t;
    }
    if (lane == 63) wsum[wid] = incl;
    __syncthreads();
    int wprefix = 0;
    #pragma unroll
    for (int w = 0; w < 4; ++w)
        if (w < wid) wprefix += wsum[w];
    if ((int)threadIdx.x < nb) bsums[threadIdx.x] = wprefix + incl - v;
    if (threadIdx.x == 255) *total = wprefix + incl;
}

__global__ void scan3_k(int* __restrict__ out, const int* __restrict__ bsums, int n) {
    int add = bsums[blockIdx.x];
    int base = blockIdx.x * SCAN_TILE + (int)threadIdx.x * SCAN_ITEMS;
    #pragma unroll
    for (int i = 0; i < SCAN_ITEMS; ++i)
        if (base + i < n) out[base + i] += add;
}

__global__ void gofs_search_k(const int* __restrict__ batch, int* __restrict__ gofs,
                              int n, int G) {
    int g = blockIdx.x * blockDim.x + threadIdx.x;
    if (g > G) return;
    if (g == G) { gofs[G] = n; return; }
    int lo = 0, hi = n;
    while (lo < hi) {
        int mid = (lo + hi) >> 1;
        if (batch[mid] < g) lo = mid + 1; else hi = mid;
    }
    gofs[g] = lo;
}

__global__ void fill_csr_k(const int* __restrict__ src, const int* __restrict__ dst,
                           const int* __restrict__ row_ofs, int* __restrict__ cursor,
                           int* __restrict__ csr, int E) {
    int e = blockIdx.x * blockDim.x + threadIdx.x;
    if (e >= E) return;
    int d = dst[e];
    int pos = atomicAdd(&cursor[d], 1);
    csr[row_ofs[d] + pos] = src[e];
}

// ---------------------------------------------------------------- converts
__global__ void wt_concat_k(const float* __restrict__ Wl, const float* __restrict__ Wr,
                            unsigned short* __restrict__ out, int K1, int K2, int N) {
    int idx = blockIdx.x * blockDim.x + threadIdx.x;
    int KT = K1 + K2;
    if (idx >= N * KT) return;
    int n = idx / KT, k = idx % KT;
    float v = (k < K1) ? Wl[(size_t)k * N + n] : Wr[(size_t)(k - K1) * N + n];
    out[idx] = f2b(v);
}

// fp32 -> (bf16, fp8) in one pass. Thread handles 8 floats.
__global__ void f2b8_k(const float* __restrict__ in, unsigned short* __restrict__ outb,
                       unsigned char* __restrict__ out8, size_t n8) {
    size_t i = (size_t)blockIdx.x * blockDim.x + threadIdx.x;
    if (i >= n8) return;
    float4 a = ((const float4*)in)[i * 2];
    float4 b = ((const float4*)in)[i * 2 + 1];
    unsigned short ob[8];
    ob[0] = f2b(a.x); ob[1] = f2b(a.y); ob[2] = f2b(a.z); ob[3] = f2b(a.w);
    ob[4] = f2b(b.x); ob[5] = f2b(b.y); ob[6] = f2b(b.z); ob[7] = f2b(b.w);
    ((uint4*)outb)[i] = *(const uint4*)ob;
    int w0 = 0, w1 = 0;
    w0 = __builtin_amdgcn_cvt_pk_fp8_f32(a.x, a.y, w0, false);
    w0 = __builtin_amdgcn_cvt_pk_fp8_f32(a.z, a.w, w0, true);
    w1 = __builtin_amdgcn_cvt_pk_fp8_f32(b.x, b.y, w1, false);
    w1 = __builtin_amdgcn_cvt_pk_fp8_f32(b.z, b.w, w1, true);
    uint2 o8; o8.x = (unsigned int)w0; o8.y = (unsigned int)w1;
    ((uint2*)out8)[i] = o8;
}

// bf16 -> fp8 e4m3 (HW cvt). Each thread: 16 bf16 in (32B) -> 16 fp8 out (16B).
__global__ void b2f8_k(const unsigned short* __restrict__ in, unsigned char* __restrict__ out,
                       size_t n16) {
    size_t i = (size_t)blockIdx.x * blockDim.x + threadIdx.x;
    if (i >= n16) return;
    uint4 v0 = ((const uint4*)in)[i * 2];
    uint4 v1 = ((const uint4*)in)[i * 2 + 1];
    const unsigned int* q = (const unsigned int*)&v0;
    const unsigned int* r = (const unsigned int*)&v1;
    uint4 o;
    unsigned int* po = (unsigned int*)&o;
    #pragma unroll
    for (int t = 0; t < 2; ++t) {
        int w = 0;
        w = __builtin_amdgcn_cvt_pk_fp8_f32(b2f((unsigned short)(q[t * 2] & 0xFFFF)),
                                            b2f((unsigned short)(q[t * 2] >> 16)), w, false);
        w = __builtin_amdgcn_cvt_pk_fp8_f32(b2f((unsigned short)(q[t * 2 + 1] & 0xFFFF)),
                                            b2f((unsigned short)(q[t * 2 + 1] >> 16)), w, true);
        po[t] = (unsigned int)w;
    }
    #pragma unroll
    for (int t = 0; t < 2; ++t) {
        int w = 0;
        w = __builtin_amdgcn_cvt_pk_fp8_f32(b2f((unsigned short)(r[t * 2] & 0xFFFF)),
                                            b2f((unsigned short)(r[t * 2] >> 16)), w, false);
        w = __builtin_amdgcn_cvt_pk_fp8_f32(b2f((unsigned short)(r[t * 2 + 1] & 0xFFFF)),
                                            b2f((unsigned short)(r[t * 2 + 1] >> 16)), w, true);
        po[2 + t] = (unsigned int)w;
    }
    ((uint4*)out)[i] = o;
}

// ---------------------------------------------------------------- mean aggregation
// fp8 in [n,C] -> bf16 mean out [n,C]. One wave per node; GL=C/16 lanes x 16B per
// gather, NG=64/GL edge-groups, 2x unroll. Cross-group shfl_xor reduce.
template <int C>
__global__ void agg_f8_k(const unsigned char* __restrict__ X8, const int* __restrict__ row_ofs,
                         const int* __restrict__ csr, unsigned short* __restrict__ out, int n) {
    constexpr int GL = C / 16;
    constexpr int NG = 64 / GL;
    int w = (int)((blockIdx.x * blockDim.x + threadIdx.x) >> 6);
    int lane = threadIdx.x & 63;
    if (w >= n) return;
    int g = lane / GL, il = lane % GL;
    int s = row_ofs[w], e = row_ofs[w + 1];
    float a[16];
    #pragma unroll
    for (int t = 0; t < 16; ++t) a[t] = 0.f;

    int j = s + g;
    for (; j + NG < e; j += 2 * NG) {
        int i0 = csr[j], i1 = csr[j + NG];
        uint4 r0 = *(const uint4*)&X8[(size_t)i0 * C + il * 16];
        uint4 r1 = *(const uint4*)&X8[(size_t)i1 * C + il * 16];
        const unsigned int* q0 = (const unsigned int*)&r0;
        const unsigned int* q1 = (const unsigned int*)&r1;
        #pragma unroll
        for (int t = 0; t < 4; ++t) {
            f32x2 lo = __builtin_amdgcn_cvt_pk_f32_fp8(q0[t], false);
            f32x2 hi = __builtin_amdgcn_cvt_pk_f32_fp8(q0[t], true);
            a[t * 4 + 0] += lo.x; a[t * 4 + 1] += lo.y;
            a[t * 4 + 2] += hi.x; a[t * 4 + 3] += hi.y;
        }
        #pragma unroll
        for (int t = 0; t < 4; ++t) {
            f32x2 lo = __builtin_amdgcn_cvt_pk_f32_fp8(q1[t], false);
            f32x2 hi = __builtin_amdgcn_cvt_pk_f32_fp8(q1[t], true);
            a[t * 4 + 0] += lo.x; a[t * 4 + 1] += lo.y;
            a[t * 4 + 2] += hi.x; a[t * 4 + 3] += hi.y;
        }
    }
    if (j < e) {
        int i0 = csr[j];
        uint4 r0 = *(const uint4*)&X8[(size_t)i0 * C + il * 16];
        const unsigned int* q0 = (const unsigned int*)&r0;
        #pragma unroll
        for (int t = 0; t < 4; ++t) {
            f32x2 lo = __builtin_amdgcn_cvt_pk_f32_fp8(q0[t], false);
            f32x2 hi = __builtin_amdgcn_cvt_pk_f32_fp8(q0[t], true);
            a[t * 4 + 0] += lo.x; a[t * 4 + 1] += lo.y;
            a[t * 4 + 2] += hi.x; a[t * 4 + 3] += hi.y;
        }
    }

    #pragma unroll
    for (int m = GL; m < 64; m <<= 1)
        #pragma unroll
        for (int t = 0; t < 16; ++t) a[t] += __shfl_xor(a[t], m, 64);

    if (g == 0) {
        float inv = 1.0f / (float)max(e - s, 1);
        uint4 o0, o1;
        unsigned short* p0 = (unsigned short*)&o0;
        unsigned short* p1 = (unsigned short*)&o1;
        #pragma unroll
        for (int t = 0; t < 8; ++t) p0[t] = f2b(a[t] * inv);
        #pragma unroll
        for (int t = 0; t < 8; ++t) p1[t] = f2b(a[8 + t] * inv);
        *(uint4*)&out[(size_t)w * C + il * 16] = o0;
        *(uint4*)&out[(size_t)w * C + il * 16 + 8] = o1;
    }
}

// pool: bf16 input [N,256] -> fp32 pooled [G,256]; one wave per graph
__global__ void pool_mean_k(const unsigned short* __restrict__ H, const int* __restrict__ gofs,
                            float* __restrict__ pooled, int G) {
    int g = (int)((blockIdx.x * blockDim.x + threadIdx.x) >> 6);
    int lane = threadIdx.x & 63;
    if (g >= G) return;
    int s = gofs[g], e = gofs[g + 1];
    float a0 = 0.f, a1 = 0.f, a2 = 0.f, a3 = 0.f;
    for (int r = s; r < e; ++r) {
        ushort4 t = ((const ushort4*)(H + (size_t)r * HID))[lane];
        a0 += b2f(t.x); a1 += b2f(t.y); a2 += b2f(t.z); a3 += b2f(t.w);
    }
    float inv = 1.0f / (float)max(e - s, 1);
    float4 o; o.x = a0 * inv; o.y = a1 * inv; o.z = a2 * inv; o.w = a3 * inv;
    ((float4*)(pooled + (size_t)g * HID))[lane] = o;
}

// ---------------------------------------------------------------- bf16 MFMA GEMM
// C[M,Nfull] = act( [A1|A2][M,K1+K2] @ Bt[Nfull,K1+K2]^T + bias )
// 128x128 tile, 4 waves 2x2, each wave 4x4 frags of 16x16x32, BK=32.
// Staging via global_load_lds width=16 (LDS layout linear in chunk index).
__launch_bounds__(256)
__global__ void mfma_gemm_k(const unsigned short* __restrict__ A1, int K1,
                            const unsigned short* __restrict__ A2, int K2,
                            const unsigned short* __restrict__ Bt,
                            const float* __restrict__ bias, int M, int Nfull,
                            void* __restrict__ Cptr, int c_bf16, int do_relu) {
    __shared__ short ldsA[128 * 32];
    __shared__ short ldsB[128 * 32];
    int tid = threadIdx.x, lane = tid & 63;
    int wid = tid >> 6, wm = wid >> 1, wn = wid & 1;
    int row0 = blockIdx.x * 128, col0 = blockIdx.y * 128;
    int q = lane >> 4, l15 = lane & 15;
    int KT = K1 + K2;

    int rr = tid >> 2;            // 0..63 row within half-tile
    int c8 = (tid & 3) * 8;       // k-chunk offset (shorts)
    int dof = wid * 512;          // wave-uniform LDS base (shorts) within half-pass

    f32x4 acc[4][4] = {};

    for (int kt = 0; kt < KT; kt += 32) {
        const unsigned short* Asrc; int kk, Ks;
        if (kt < K1) { Asrc = A1; kk = kt; Ks = K1; }
        else         { Asrc = A2; kk = kt - K1; Ks = K2; }
        #pragma unroll
        for (int h = 0; h < 2; ++h) {
            int r = h * 64 + rr;
            int gr = min(row0 + r, M - 1);
            GLOAD_LDS16(Asrc + (size_t)gr * Ks + kk + c8, ldsA + h * 2048 + dof);
            GLOAD_LDS16(Bt + (size_t)(col0 + r) * KT + kt + c8, ldsB + h * 2048 + dof);
        }
        __syncthreads();

        bf16x8 af[4], bfr[4];
        #pragma unroll
        for (int i = 0; i < 4; ++i)
            af[i] = *(const bf16x8*)&ldsA[(wm * 64 + i * 16 + l15) * 32 + q * 8];
        #pragma unroll
        for (int j = 0; j < 4; ++j)
            bfr[j] = *(const bf16x8*)&ldsB[(wn * 64 + j * 16 + l15) * 32 + q * 8];
        #pragma unroll
        for (int i = 0; i < 4; ++i)
            #pragma unroll
            for (int j = 0; j < 4; ++j)
                acc[i][j] = __builtin_amdgcn_mfma_f32_16x16x32_bf16(af[i], bfr[j], acc[i][j], 0, 0, 0);
        __syncthreads();
    }

    // epilogue: D layout col=lane&15, row=quad*4+reg
    #pragma unroll
    for (int i = 0; i < 4; ++i) {
        #pragma unroll
        for (int reg = 0; reg < 4; ++reg) {
            int r = row0 + wm * 64 + i * 16 + q * 4 + reg;
            if (r < M) {
                #pragma unroll
                for (int j = 0; j < 4; ++j) {
                    int cc = col0 + wn * 64 + j * 16 + l15;
                    float v = acc[i][j][reg] + bias[cc];
                    if (do_relu) v = fmaxf(v, 0.f);
                    if (c_bf16) ((unsigned short*)Cptr)[(size_t)r * Nfull + cc] = f2b(v);
                    else        ((float*)Cptr)[(size_t)r * Nfull + cc] = v;
                }
            }
        }
    }
}

// ---------------------------------------------------------------- fp32 GEMM (head only)
#define BM_ 64
#define BK_ 16

template <int BN_>
__launch_bounds__(256)
__global__ void gemm2_k(const float* __restrict__ A1, const float* __restrict__ B1, int K1,
                        const float* __restrict__ bias, float* __restrict__ C,
                        int M, int N, int do_relu) {
    constexpr int TCOLS = BN_ / 8;
    constexpr int TROWS = 256 / TCOLS;
    constexpr int TM = BM_ / TROWS;
    __shared__ float As[BK_][BM_ + 4];
    __shared__ float Bs[BK_][BN_ + 4];
    int tid = threadIdx.x;
    int row0 = blockIdx.x * BM_;
    int col0 = blockIdx.y * BN_;
    int tx = tid % TCOLS, ty = tid / TCOLS;

    float acc[TM][8];
    #pragma unroll
    for (int i = 0; i < TM; ++i)
        #pragma unroll
        for (int j = 0; j < 8; ++j) acc[i][j] = 0.f;

    int ar = tid >> 2;
    int ak = (tid & 3) * 4;

    for (int kt = 0; kt < K1; kt += BK_) {
        {
            int r = row0 + ar;
            int rc = min(r, M - 1);
            float4 v = *(const float4*)(A1 + (size_t)rc * K1 + kt + ak);
            As[ak + 0][ar] = v.x;
            As[ak + 1][ar] = v.y;
            As[ak + 2][ar] = v.z;
            As[ak + 3][ar] = v.w;
        }
        {
            #pragma unroll
            for (int h = 0; h < BN_ / 64; ++h) {
                int idx = h * 256 + tid;
                int kr = idx / (BN_ / 4);
                int c4 = idx % (BN_ / 4);
                float4 v = *(const float4*)(B1 + (size_t)(kt + kr) * N + col0 + c4 * 4);
                *(float4*)&Bs[kr][c4 * 4] = v;
            }
        }
        __syncthreads();

        #pragma unroll
        for (int k = 0; k < BK_; ++k) {
            float a[TM], b[8];
            #pragma unroll
            for (int v = 0; v < TM / 4; ++v)
                *(float4*)&a[v * 4] = *(const float4*)&As[k][ty * TM + v * 4];
            *(float4*)&b[0] = *(const float4*)&Bs[k][tx * 8];
            *(float4*)&b[4] = *(const float4*)&Bs[k][tx * 8 + 4];
            #pragma unroll
            for (int i = 0; i < TM; ++i)
                #pragma unroll
                for (int j = 0; j < 8; ++j) acc[i][j] = fmaf(a[i], b[j], acc[i][j]);
        }
        __syncthreads();
    }

    float bv[8];
    #pragma unroll
    for (int j = 0; j < 8; ++j) bv[j] = bias[col0 + tx * 8 + j];
    #pragma unroll
    for (int i = 0; i < TM; ++i) {
        int r = row0 + ty * TM + i;
        if (r < M) {
            float* cp = C + (size_t)r * N + col0 + tx * 8;
            float o[8];
            #pragma unroll
            for (int j = 0; j < 8; ++j) {
                float v = acc[i][j] + bv[j];
                o[j] = do_relu ? fmaxf(v, 0.f) : v;
            }
            *(float4*)(cp + 0) = *(float4*)&o[0];
            *(float4*)(cp + 4) = *(float4*)&o[4];
        }
    }
}

// ---------------------------------------------------------------- launcher
extern "C" void kernel_launch(void* const* d_in, const int* in_sizes, int n_in,
                              void* d_out, int out_size, void* d_ws, size_t ws_size,
                              hipStream_t stream) {
    const float* x    = (const float*)d_in[0];
    const int*   ei   = (const int*)d_in[1];
    const int*   batch= (const int*)d_in[2];
    const float* W1l  = (const float*)d_in[3];
    const float* b1   = (const float*)d_in[4];
    const float* W1r  = (const float*)d_in[5];
    const float* W2l  = (const float*)d_in[6];
    const float* b2   = (const float*)d_in[7];
    const float* W2r  = (const float*)d_in[8];
    const float* W3   = (const float*)d_in[9];
    const float* b3   = (const float*)d_in[10];
    const float* W4   = (const float*)d_in[11];
    const float* b4   = (const float*)d_in[12];
    float* out = (float*)d_out;

    const int N = N_NODES, E = N_EDGES, G = N_GRAPHS;
    const int* src = ei;
    const int* dst = ei + E;

    char* ws = (char*)d_ws;
    size_t off = 0;
    auto alloc = [&](size_t bytes) -> char* {
        off = (off + 255) & ~(size_t)255;
        char* p = ws + off;
        off += bytes;
        return p;
    };
    int* deg     = (int*)alloc((size_t)N * 4);
    int* cursor  = (int*)alloc((size_t)N * 4);
    size_t zero_span = (size_t)((char*)(cursor + N) - (char*)deg);
    int* row_ofs = (int*)alloc((size_t)(N + 1) * 4);
    int* gofs    = (int*)alloc((size_t)(G + 1) * 4);
    int* bsums   = (int*)alloc(256 * 4);
    int* csr     = (int*)alloc((size_t)E * 4);
    unsigned short* xb    = (unsigned short*)alloc((size_t)N * IN_CH * 2);
    unsigned short* mean1 = (unsigned short*)alloc((size_t)N * IN_CH * 2);
    unsigned short* h1    = (unsigned short*)alloc((size_t)N * HID * 2);
    unsigned short* mean2 = (unsigned short*)alloc((size_t)N * HID * 2);
    unsigned short* h2    = xb;  // xb+mean1 contiguous span reused for h2 [N,256]
    unsigned char*  x8    = (unsigned char*)alloc((size_t)N * IN_CH);
    unsigned char*  h1f8  = (unsigned char*)alloc((size_t)N * HID);
    unsigned short* W1T   = (unsigned short*)alloc((size_t)HID * (IN_CH + IN_CH) * 2);
    unsigned short* W2T   = (unsigned short*)alloc((size_t)HID * (HID + HID) * 2);
    float* pooled = (float*)alloc((size_t)G * HID * 4);
    float* hidden = (float*)alloc((size_t)G * HID * 4);
    (void)ws_size;

    hipMemsetAsync(deg, 0, zero_span, stream);

    count_edges_k<<<(E + 255) / 256, 256, 0, stream>>>(dst, deg, E);

    const int nb = (N + SCAN_TILE - 1) / SCAN_TILE;
    scan1_k<<<nb, 256, 0, stream>>>(deg, row_ofs, bsums, N);
    scan2_k<<<1, 256, 0, stream>>>(bsums, nb, row_ofs + N);
    scan3_k<<<nb, 256, 0, stream>>>(row_ofs, bsums, N);

    gofs_search_k<<<(G + 256) / 256, 256, 0, stream>>>(batch, gofs, N, G);

    fill_csr_k<<<(E + 255) / 256, 256, 0, stream>>>(src, dst, row_ofs, cursor, csr, E);

    wt_concat_k<<<(HID * 2 * IN_CH + 255) / 256, 256, 0, stream>>>(W1l, W1r, W1T, IN_CH, IN_CH, HID);
    wt_concat_k<<<(HID * 2 * HID + 255) / 256, 256, 0, stream>>>(W2l, W2r, W2T, HID, HID, HID);
    f2b8_k<<<(int)(((size_t)N * IN_CH / 8 + 255) / 256), 256, 0, stream>>>(
        x, xb, x8, (size_t)N * IN_CH / 8);

    const int MB = (N + 127) / 128;

    // layer 1: mean1 = mean-agg(x8) [fp8 gather]; h1 = relu([mean1|xb] @ W1T^T + b1)
    agg_f8_k<IN_CH><<<(N + 3) / 4, 256, 0, stream>>>(x8, row_ofs, csr, mean1, N);
    mfma_gemm_k<<<dim3(MB, HID / 128), 256, 0, stream>>>(
        mean1, IN_CH, xb, IN_CH, W1T, b1, N, HID, h1, 1, 1);

    // fp8 mirror of h1 for the layer-2 gather
    b2f8_k<<<(int)(((size_t)N * HID / 16 + 255) / 256), 256, 0, stream>>>(
        h1, h1f8, (size_t)N * HID / 16);

    // layer 2: mean2 = mean-agg(h1f8) [fp8 gather]; h2 = relu([mean2|h1] @ W2T^T + b2)
    agg_f8_k<HID><<<(N + 3) / 4, 256, 0, stream>>>(h1f8, row_ofs, csr, mean2, N);
    mfma_gemm_k<<<dim3(MB, HID / 128), 256, 0, stream>>>(
        mean2, HID, h1, HID, W2T, b2, N, HID, h2, 1, 1);

    // global mean pool (bf16 in, fp32 out)
    pool_mean_k<<<(G + 3) / 4, 256, 0, stream>>>(h2, gofs, pooled, G);

    // MLP head (fp32)
    gemm2_k<HID><<<dim3(G / BM_, 1), 256, 0, stream>>>(
        pooled, W3, HID, b3, hidden, G, HID, 1);
    gemm2_k<OUT_CH><<<dim3(G / BM_, 1), 256, 0, stream>>>(
        hidden, W4, HID, b4, out, G, OUT_CH, 0);
}